// Round 9
// baseline (1391.755 us; speedup 1.0000x reference)
//
#include <hip/hip_runtime.h>

// BiLSTM-CRF on MI355X. Round 9: K3 cell update fused into MFMA-owner lanes
// (lq==0): no xbuf, ONE barrier/step, acc stays in registers. K2 epilogue
// re-laid to [dir][s][b][j][g] so K3 gate loads are ushort4.

#define DEV __device__ __forceinline__
typedef unsigned short u16;
typedef unsigned int   u32;
typedef unsigned char  u8;
typedef signed char    s8;
using short8  = __attribute__((ext_vector_type(8))) short;
using ushort4v= __attribute__((ext_vector_type(4))) unsigned short;
using f32x4   = __attribute__((ext_vector_type(4))) float;
using int4v   = __attribute__((ext_vector_type(4))) int;

DEV float bf2f(u16 u){ union{u32 i; float f;} v; v.i = ((u32)u)<<16; return v.f; }
DEV u16 f2bf(float f){ u32 x = __float_as_uint(f); return (u16)((x + 0x7fffu + ((x>>16)&1u)) >> 16); }
DEV float sigf(float x){ return __builtin_amdgcn_rcpf(1.f + __expf(-x)); }
DEV float tanh_f(float x){ return 1.f - 2.f*__builtin_amdgcn_rcpf(__expf(2.f*x) + 1.f); }

typedef __attribute__((address_space(1))) const u32 GU;
typedef __attribute__((address_space(3))) u32 LU;
DEV void gld_lds16(const void* g, void* l){
  __builtin_amdgcn_global_load_lds((GU*)g, (LU*)l, 16, 0, 0);
}
// LDS-only barrier: no vmcnt drain (global stores/prefetch float across)
DEV void bar_l(){
  __builtin_amdgcn_sched_barrier(0);
  asm volatile("s_waitcnt lgkmcnt(0)" ::: "memory");
  __builtin_amdgcn_s_barrier();
  __builtin_amdgcn_sched_barrier(0);
}

// ---------------- ws layout (aliased; total ~170MB) ----------------
static const size_t OFF_GI   = 0;
static const size_t OFF_P    = 0;
static const size_t OFF_DL   = OFF_P  + (size_t)32768*16*4;
static const size_t OFF_PSI  = OFF_DL + (size_t)32768*16*4;
static const size_t OFF_B    = (size_t)134217728;
static const size_t OFF_WIH  = OFF_B    + (size_t)33554432;
static const size_t OFF_WQ   = OFF_WIH  + (size_t)1703936;   // 512KB i8 frags
static const size_t OFF_SC   = OFF_WQ   + (size_t)524288;    // 8KB scales
static const size_t OFF_BIAS = OFF_SC   + 8192;
static const size_t OFF_WFC  = OFF_BIAS + 8192;
static const size_t REQUIRED = OFF_WFC  + 256;

// ---------------- K0: pack W_ih (f32 -> bf16 [2048][416]) ----------------
__global__ void k0_pack(const float* __restrict__ wihf, const float* __restrict__ wihb,
                        u16* __restrict__ wih)
{
  int n = blockIdx.x, tid = threadIdx.x;
  const float* src = (n < 1024) ? (wihf + (size_t)n*400) : (wihb + (size_t)(n-1024)*400);
  u32* dst = (u32*)(wih + (size_t)n*416);
  if (tid < 208){
    int j = tid*2;
    u32 v = 0u;
    if (j < 400){
      float2 f = *(const float2*)(src + j);
      v = (u32)f2bf(f.x) | ((u32)f2bf(f.y) << 16);
    }
    dst[tid] = v;
  }
}

// ---------------- K0q: quantize W_hh rows to i8 MFMA fragments ----------------
__global__ __launch_bounds__(256) void k0q(
    const float* __restrict__ whhf, const float* __restrict__ whhb,
    s8* __restrict__ wq, float* __restrict__ sc2)
{
  const int row = blockIdx.x*4 + (threadIdx.x >> 6);
  const int lane = threadIdx.x & 63;
  const float* src = (row < 1024) ? (whhf + (size_t)row*256)
                                  : (whhb + (size_t)(row-1024)*256);
  f32x4 v = *(const f32x4*)(src + lane*4);
  float m = fmaxf(fmaxf(fabsf(v[0]), fabsf(v[1])), fmaxf(fabsf(v[2]), fabsf(v[3])));
  #pragma unroll
  for (int d = 1; d < 64; d <<= 1) m = fmaxf(m, __shfl_xor(m, d, 64));
  float inv = 127.f / (m + 1e-30f);
  u32 pack = 0;
  #pragma unroll
  for (int e = 0; e < 4; e++){
    int q = (int)rintf(v[e]*inv);
    q = q > 127 ? 127 : (q < -127 ? -127 : q);
    pack |= ((u32)(u8)(s8)q) << (8*e);
  }
  const int dir = row >> 10, n = row & 1023;
  const int g = n >> 8, j = n & 255, w2 = j >> 4, lr2 = j & 15;
  const int kk = lane >> 4, lq2 = (lane >> 2) & 3, e4 = lane & 3;
  u32* wq32 = (u32*)wq;
  wq32[dir*65536 + (((g*16 + w2)*4 + kk)*64 + lq2*16 + lr2)*4 + e4] = pack;
  if (lane == 0) sc2[row] = m * (1.f/16129.f);
}

// ---------------- K0b: bias sums (fp32) + wfc = fc_w @ wd (parallel) ----------------
__global__ void k0_misc(const float* bihf, const float* bhhf, const float* bihb, const float* bhhb,
                        const float* fcw, const float* wdp, float* bias, float* wfc)
{
  __shared__ float red[256];
  int tid = threadIdx.x;
  for (int n = tid; n < 2048; n += 256){
    bias[n] = (n < 1024) ? (bihf[n] + bhhf[n]) : (bihb[n-1024] + bhhb[n-1024]);
  }
  const int cur = tid & 15, part = tid >> 4;
  float s = 0.f;
  for (int k = part*32; k < part*32 + 32; k++) s += fcw[cur*512 + k] * wdp[k];
  red[tid] = s;
  __syncthreads();
  if (tid < 16){
    float t = 0.f;
    #pragma unroll
    for (int p = 0; p < 16; p++) t += red[p*16 + tid];
    wfc[tid] = t;
  }
}

// ---------------- K1: features -> feat[s*64+b][416] bf16 ----------------
__global__ __launch_bounds__(256) void k1_feat(
    const int* __restrict__ X, const int* __restrict__ tg, const int* __restrict__ ch,
    const float* __restrict__ etab, const float* __restrict__ ttab, const float* __restrict__ ctab,
    const float* __restrict__ cw, const float* __restrict__ cb, u16* __restrict__ feat)
{
  const int sb = blockIdx.x, b = blockIdx.y, tid = threadIdx.x;
  __shared__ float ce_s[66*60];
  __shared__ float w_s[150*52];
  for (int i = tid; i < 600; i += 256){
    int wl = i/150, j = i - wl*150;
    int s = sb*4 + wl;
    int idx = X[b*512 + s];
    float2 f = *(const float2*)(etab + (size_t)idx*300 + j*2);
    *(u32*)(feat + (size_t)(s*64 + b)*416 + j*2) = (u32)f2bf(f.x) | ((u32)f2bf(f.y) << 16);
  }
  for (int i = tid; i < 100; i += 256){
    int wl = i/25, j = i - wl*25;
    int s = sb*4 + wl;
    int idx = tg[b*512 + s];
    float2 f = *(const float2*)(ttab + (size_t)idx*50 + j*2);
    *(u32*)(feat + (size_t)(s*64 + b)*416 + 300 + j*2) = (u32)f2bf(f.x) | ((u32)f2bf(f.y) << 16);
  }
  if (tid < 32){
    int wl = tid>>3, j = tid&7;
    int s = sb*4 + wl;
    *(u32*)(feat + (size_t)(s*64 + b)*416 + 400 + j*2) = 0u;
  }
  for (int i = tid; i < 3300; i += 256){
    int qq = i/50, ce = i - qq*50;
    int p = sb*64 - 1 + qq;
    float v = 0.f;
    if (p >= 0 && p < 8192){
      int ci = ch[b*8192 + p];
      v = ctab[ci*50 + ce];
    }
    ce_s[qq*60 + ce] = v;
  }
  for (int i = tid; i < 7500; i += 256){
    int cc = i/150, r2 = i - cc*150;
    int ce = r2/3, dc = r2 - ce*3;
    w_s[(cc*3 + dc)*52 + ce] = cw[i];
  }
  __syncthreads();
  const int li = tid & 15, jg = tid >> 4;
  float acc[4][3];
  #pragma unroll
  for (int k=0;k<4;k++){ acc[k][0]=0.f; acc[k][1]=0.f; acc[k][2]=0.f; }
  #pragma unroll
  for (int dc = 0; dc < 3; dc++){
    for (int ceb = 0; ceb < 48; ceb += 4){
      f32x4 w0 = *(const f32x4*)&w_s[((3*jg+0)*3 + dc)*52 + ceb];
      f32x4 w1 = *(const f32x4*)&w_s[((3*jg+1)*3 + dc)*52 + ceb];
      f32x4 w2 = *(const f32x4*)&w_s[((3*jg+2)*3 + dc)*52 + ceb];
      #pragma unroll
      for (int k = 0; k < 4; k++){
        f32x4 cv = *(const f32x4*)&ce_s[(16*k + li + dc)*60 + ceb];
        #pragma unroll
        for (int e = 0; e < 4; e++){
          acc[k][0] += cv[e]*w0[e];
          acc[k][1] += cv[e]*w1[e];
          acc[k][2] += cv[e]*w2[e];
        }
      }
    }
    float w0a = w_s[((3*jg+0)*3+dc)*52 + 48], w0b = w_s[((3*jg+0)*3+dc)*52 + 49];
    float w1a = w_s[((3*jg+1)*3+dc)*52 + 48], w1b = w_s[((3*jg+1)*3+dc)*52 + 49];
    float w2a = w_s[((3*jg+2)*3+dc)*52 + 48], w2b = w_s[((3*jg+2)*3+dc)*52 + 49];
    #pragma unroll
    for (int k = 0; k < 4; k++){
      float ca = ce_s[(16*k + li + dc)*60 + 48];
      float cb2 = ce_s[(16*k + li + dc)*60 + 49];
      acc[k][0] += ca*w0a + cb2*w0b;
      acc[k][1] += ca*w1a + cb2*w1b;
      acc[k][2] += ca*w2a + cb2*w2b;
    }
  }
  #pragma unroll
  for (int m = 1; m < 16; m <<= 1)
    #pragma unroll
    for (int k=0;k<4;k++)
      #pragma unroll
      for (int c=0;c<3;c++)
        acc[k][c] = fmaxf(acc[k][c], __shfl_xor(acc[k][c], m, 64));
  if (li == 0){
    #pragma unroll
    for (int k=0;k<4;k++)
      #pragma unroll
      for (int c=0;c<3;c++){
        int cc = 3*jg + c;
        int s = sb*4 + k;
        feat[(size_t)(s*64 + b)*416 + 350 + cc] = f2bf(acc[k][c] + cb[cc]);
      }
  }
  if (tid < 128){
    int pl = tid & 63, cc = 48 + (tid >> 6);
    float a2 = 0.f;
    #pragma unroll
    for (int dc = 0; dc < 3; dc++){
      for (int ceb = 0; ceb < 48; ceb += 4){
        f32x4 wv = *(const f32x4*)&w_s[(cc*3 + dc)*52 + ceb];
        f32x4 cv = *(const f32x4*)&ce_s[(pl + dc)*60 + ceb];
        a2 += cv[0]*wv[0] + cv[1]*wv[1] + cv[2]*wv[2] + cv[3]*wv[3];
      }
      a2 += ce_s[(pl+dc)*60 + 48]*w_s[(cc*3+dc)*52 + 48]
          + ce_s[(pl+dc)*60 + 49]*w_s[(cc*3+dc)*52 + 49];
    }
    #pragma unroll
    for (int m = 1; m < 16; m <<= 1) a2 = fmaxf(a2, __shfl_xor(a2, m, 64));
    if ((tid & 15) == 0){
      int s = sb*4 + ((tid & 63) >> 4);
      feat[(size_t)(s*64 + b)*416 + 350 + cc] = f2bf(a2 + cb[cc]);
    }
  }
}

// ---------------- K2: gi = bf16(feat @ wih^T + bias), layout [dir][s][b][j][g] ----------------
__global__ __launch_bounds__(256) void k2_gemm(
    const u16* __restrict__ featp, const u16* __restrict__ wihp,
    const float* __restrict__ bias, u16* __restrict__ gi)
{
  const int m0 = blockIdx.y*128, n0 = blockIdx.x*128;
  const int tid = threadIdx.x, wv = tid>>6, lane = tid&63;
  const int lr = lane & 15, lq = lane >> 4;
  const int wm = (wv>>1)*64, wn = (wv&1)*64;
  __shared__ u16 As[4096], Bs[4096];
  f32x4 acc[4][4];
  #pragma unroll
  for (int a=0;a<4;a++)
    #pragma unroll
    for (int c=0;c<4;c++) acc[a][c] = (f32x4){0.f,0.f,0.f,0.f};
  for (int k0 = 0; k0 < 416; k0 += 32){
    __syncthreads();
    #pragma unroll
    for (int i = 0; i < 2; i++){
      int c = i*4 + wv;
      gld_lds16(featp + (size_t)(m0 + c*16 + (lane>>2))*416 + k0 + (lane&3)*8, &As[c*512]);
      gld_lds16(wihp  + (size_t)(n0 + c*16 + (lane>>2))*416 + k0 + (lane&3)*8, &Bs[c*512]);
    }
    __syncthreads();
    short8 af[4], bfr[4];
    #pragma unroll
    for (int mt=0; mt<4; mt++) af[mt]  = *(const short8*)(As + (wm + mt*16 + lr)*32 + lq*8);
    #pragma unroll
    for (int nt=0; nt<4; nt++) bfr[nt] = *(const short8*)(Bs + (wn + nt*16 + lr)*32 + lq*8);
    #pragma unroll
    for (int mt=0; mt<4; mt++)
      #pragma unroll
      for (int nt=0; nt<4; nt++)
        acc[mt][nt] = __builtin_amdgcn_mfma_f32_16x16x32_bf16(af[mt], bfr[nt], acc[mt][nt], 0,0,0);
  }
  #pragma unroll
  for (int nt=0; nt<4; nt++){
    const int n = n0 + wn + nt*16 + lr;
    const float bv = bias[n];
    const int dirn = n >> 10, g = (n >> 8) & 3, j = n & 255;
    #pragma unroll
    for (int mt=0; mt<4; mt++)
      #pragma unroll
      for (int r=0; r<4; r++){
        const int m = m0 + wm + mt*16 + lq*4 + r;
        const int s = m >> 6, b = m & 63;
        gi[((size_t)((dirn*512 + s)*64 + b) << 10) + (j << 2) + g]
            = f2bf(acc[mt][nt][r] + bv);
      }
  }
}

// ---------------- K3: recurrent BiLSTM, fused cell-in-MFMA-lanes, 1 barrier/step ----------------
// 64 blocks x 512 thr. dir = blk>>5, batch rows bb=(blk&31)*2. Wave w owns
// j-slices 2w,2w+1. W_hh all in VGPR. lq==0 lanes own 4 cells each
// (2 slices x 2 rows) straight from the accumulator; ONE lgkm barrier/step.
__global__ __launch_bounds__(512, 2) void k3_lstm(
    const s8* __restrict__ wq, const float* __restrict__ sc2,
    const u16* __restrict__ gi, u16* __restrict__ hcat)
{
  const int dir = blockIdx.x >> 5;
  const int bb  = (blockIdx.x & 31) * 2;
  const int tid = threadIdx.x;
  const int w = tid >> 6, lane = tid & 63;
  const int lr = lane & 15, lq = lane >> 4;

  __shared__ s8 Hs[2][4096];   // h dbuf [16 rows (2 valid)][256], col^=(b<<4)

  const s8* wqd = wq + dir*262144;
  int4v bq[2][4][4];
  #pragma unroll
  for (int sl = 0; sl < 2; sl++)
    #pragma unroll
    for (int g = 0; g < 4; g++)
      #pragma unroll
      for (int kk = 0; kk < 4; kk++)
        bq[sl][g][kk] = *(const int4v*)(wqd + (((((g*16 + 2*w + sl)*4 + kk)*64) + lane) << 4));

  const bool act = (lq == 0);
  const int jb = 2*w*16 + lr;            // j for sl=0; sl=1 is jb+16

  float scl2[2][4];
  #pragma unroll
  for (int sl = 0; sl < 2; sl++)
    #pragma unroll
    for (int g = 0; g < 4; g++)
      scl2[sl][g] = sc2[dir*1024 + g*256 + jb + sl*16];

  *(uint2*)&Hs[0][tid*8] = (uint2){0u,0u};
  *(uint2*)&Hs[1][tid*8] = (uint2){0u,0u};

  float cst[2][2] = {{0.f,0.f},{0.f,0.f}};
  const ptrdiff_t dstep = dir ? -(ptrdiff_t)65536 : (ptrdiff_t)65536;  // +-64*1024 u16
  const u16* gp = gi + ((size_t)((dir*512 + (dir ? 511 : 0))*64 + bb) << 10);
  ushort4v gc[2][2], g1r[2][2], g2r[2][2];
  if (act){
    #pragma unroll
    for (int sl = 0; sl < 2; sl++)
      #pragma unroll
      for (int r = 0; r < 2; r++){
        gc[sl][r]  = *(const ushort4v*)(gp + r*1024 + (jb + sl*16)*4);
        g1r[sl][r] = *(const ushort4v*)(gp + dstep + r*1024 + (jb + sl*16)*4);
      }
  }
  const u16* gpref = gp + dstep;
  __syncthreads();

  #pragma unroll 1
  for (int t = 0; t < 512; t++){
    const int s = dir ? (511 - t) : t;
    // prefetch step t+2's gate inputs (active lanes only)
    if (t + 2 < 512) gpref += dstep;
    if (act){
      #pragma unroll
      for (int sl = 0; sl < 2; sl++)
        #pragma unroll
        for (int r = 0; r < 2; r++)
          g2r[sl][r] = *(const ushort4v*)(gpref + r*1024 + (jb + sl*16)*4);
    }
    // MFMA phase (weights in VGPR, h from LDS)
    const s8* hb = Hs[t & 1];
    int4v aq[4];
    #pragma unroll
    for (int kk = 0; kk < 4; kk++)
      aq[kk] = *(const int4v*)(hb + lr*256 + ((kk*64 + lq*16) ^ (lr << 4)));
    int4v acc[2][4];
    #pragma unroll
    for (int sl = 0; sl < 2; sl++)
      #pragma unroll
      for (int g = 0; g < 4; g++) acc[sl][g] = (int4v){0,0,0,0};
    #pragma unroll
    for (int kk = 0; kk < 4; kk++)
      #pragma unroll
      for (int sl = 0; sl < 2; sl++)
        #pragma unroll
        for (int g = 0; g < 4; g++)
          acc[sl][g] = __builtin_amdgcn_mfma_i32_16x16x64_i8(aq[kk], bq[sl][g][kk], acc[sl][g], 0,0,0);
    // fused cell update on owner lanes (C rows 0,1 live in lq==0, reg r)
    if (act){
      s8* hw = Hs[(t + 1) & 1];
      #pragma unroll
      for (int sl = 0; sl < 2; sl++){
        const int j = jb + sl*16;
        #pragma unroll
        for (int r = 0; r < 2; r++){
          float g4[4];
          #pragma unroll
          for (int g = 0; g < 4; g++)
            g4[g] = bf2f((u16)gc[sl][r][g]) + (float)acc[sl][g][r] * scl2[sl][g];
          float iv = sigf(g4[0]), fv = sigf(g4[1]);
          float gg = tanh_f(g4[2]), ov = sigf(g4[3]);
          float c = fv*cst[sl][r] + iv*gg;
          cst[sl][r] = c;
          float h = ov * tanh_f(c);
          hcat[(size_t)(s*64 + bb + r)*512 + dir*256 + j] = f2bf(h);
          hw[r*256 + (j ^ (r << 4))] = (s8)(int)rintf(h * 127.f);
        }
      }
      #pragma unroll
      for (int sl = 0; sl < 2; sl++)
        #pragma unroll
        for (int r = 0; r < 2; r++){ gc[sl][r] = g1r[sl][r]; g1r[sl][r] = g2r[sl][r]; }
    }
    bar_l();   // single barrier: Hs[t+1] writes visible to all waves
  }
}

// ---------------- K4: P = Hcat @ fc_w^T + fc_b + lm*wfc  [32768 x 16] fp32 ----------------
__global__ __launch_bounds__(256) void k4_fc(
    const u16* __restrict__ hcat, const float* __restrict__ fcw, const float* __restrict__ fcb,
    const float* __restrict__ lmp, const float* __restrict__ wfc, float* __restrict__ Pout)
{
  const int wv = threadIdx.x >> 6, lane = threadIdx.x & 63;
  const int lr = lane & 15, lq = lane >> 4;
  const int mt = blockIdx.x*4 + wv;
  short8 bfr[16];
  #pragma unroll
  for (int kk = 0; kk < 16; kk++){
    const float* wr = fcw + (size_t)lr*512 + kk*32 + lq*8;
    f32x4 w0 = *(const f32x4*)wr;
    f32x4 w1 = *(const f32x4*)(wr + 4);
    short8 sv;
    #pragma unroll
    for (int e = 0; e < 4; e++){ sv[e] = (short)f2bf(w0[e]); sv[4+e] = (short)f2bf(w1[e]); }
    bfr[kk] = sv;
  }
  f32x4 acc = (f32x4){0.f,0.f,0.f,0.f};
  #pragma unroll
  for (int kk = 0; kk < 16; kk++){
    short8 af = *(const short8*)(hcat + (size_t)(mt*16 + lr)*512 + kk*32 + lq*8);
    acc = __builtin_amdgcn_mfma_f32_16x16x32_bf16(af, bfr[kk], acc, 0,0,0);
  }
  const int cur = lr;
  float fb = fcb[cur];
  float wf = wfc[cur];
  #pragma unroll
  for (int r = 0; r < 4; r++){
    int m = mt*16 + lq*4 + r;
    int b = m & 63, s = m >> 6;
    float lmv = lmp[b*512 + s];
    Pout[(size_t)m*16 + cur] = acc[r] + fb + lmv*wf;
  }
}

// ---------------- K5: Viterbi — de-scratched (static regs, 4x unroll) ----------------
__global__ __launch_bounds__(64) void k5_vit(
    const float* __restrict__ Pg, const float* __restrict__ Am,
    float* __restrict__ dout, float* __restrict__ dl, u8* __restrict__ psi)
{
  const int b = blockIdx.x, lane = threadIdx.x;
  const int cur = lane >> 2, q = lane & 3;
  float Ar[4];
  #pragma unroll
  for (int r = 0; r < 4; r++) Ar[r] = Am[(4*q + r)*16 + cur];
  float val = Pg[(size_t)b*16 + cur];
  if (q == 0) dl[(size_t)b*16 + cur] = val;

#define FSTEP(X, S) { \
    float best = -3.0e38f; int bi = 0; \
    _Pragma("unroll") \
    for (int r = 0; r < 4; r++){ \
      float dp = __shfl(val, (4*q + r)*4, 64); \
      float sc = (dp + Ar[r]) + (X); \
      if (sc > best){ best = sc; bi = 4*q + r; } \
    } \
    { float ov = __shfl_xor(best, 1, 64); int oi = __shfl_xor(bi, 1, 64); \
      if (ov > best || (ov == best && oi < bi)){ best = ov; bi = oi; } } \
    { float ov = __shfl_xor(best, 2, 64); int oi = __shfl_xor(bi, 2, 64); \
      if (ov > best || (ov == best && oi < bi)){ best = ov; bi = oi; } } \
    val = best; \
    if (q == 0){ \
      dl[(size_t)((S)*64 + b)*16 + cur] = best; \
      psi[(size_t)((S)*64 + b)*16 + cur] = (u8)bi; \
    } }

  float x0 = Pg[(size_t)(1*64 + b)*16 + cur];
  float x1 = Pg[(size_t)(2*64 + b)*16 + cur];
  float x2 = Pg[(size_t)(3*64 + b)*16 + cur];
  float x3 = Pg[(size_t)(4*64 + b)*16 + cur];
  for (int s = 1; s < 512; s += 4){
    FSTEP(x0, s);
    if (s + 4 < 512) x0 = Pg[(size_t)((s+4)*64 + b)*16 + cur];
    if (s + 1 < 512) FSTEP(x1, s+1);
    if (s + 5 < 512) x1 = Pg[(size_t)((s+5)*64 + b)*16 + cur];
    if (s + 2 < 512) FSTEP(x2, s+2);
    if (s + 6 < 512) x2 = Pg[(size_t)((s+6)*64 + b)*16 + cur];
    if (s + 3 < 512) FSTEP(x3, s+3);
    if (s + 7 < 512) x3 = Pg[(size_t)((s+7)*64 + b)*16 + cur];
  }
#undef FSTEP

  float bv = val; int bix = cur;
  #pragma unroll
  for (int m = 1; m < 64; m <<= 1){
    float ov = __shfl_xor(bv, m, 64);
    int   oi = __shfl_xor(bix, m, 64);
    if (ov > bv || (ov == bv && oi < bix)){ bv = ov; bix = oi; }
  }
  int tag = bix;
  float score = bv;
  if (lane == 0) dout[b*512 + 511] = (float)tag;

#define BSTEP(PV, DV, T) { \
    int prev = __shfl((PV), tag, 64); \
    score += __shfl((DV), prev, 64); \
    if (lane == 0) dout[b*512 + (T)] = (float)prev; \
    tag = prev; }

  int   p0 = 0, p1 = 0, p2 = 0, p3 = 0;
  float d0 = 0.f, d1 = 0.f, d2 = 0.f, d3 = 0.f;
  if (lane < 16){
    p0 = psi[(size_t)(511*64 + b)*16 + lane]; d0 = dl[(size_t)(510*64 + b)*16 + lane];
    p1 = psi[(size_t)(510*64 + b)*16 + lane]; d1 = dl[(size_t)(509*64 + b)*16 + lane];
    p2 = psi[(size_t)(509*64 + b)*16 + lane]; d2 = dl[(size_t)(508*64 + b)*16 + lane];
    p3 = psi[(size_t)(508*64 + b)*16 + lane]; d3 = dl[(size_t)(507*64 + b)*16 + lane];
  }
  for (int t = 510; t >= 0; t -= 4){
    BSTEP(p0, d0, t);
    if (t - 4 >= 0 && lane < 16){
      p0 = psi[(size_t)((t-3)*64 + b)*16 + lane]; d0 = dl[(size_t)((t-4)*64 + b)*16 + lane];
    }
    if (t - 1 >= 0) BSTEP(p1, d1, t-1);
    if (t - 5 >= 0 && lane < 16){
      p1 = psi[(size_t)((t-4)*64 + b)*16 + lane]; d1 = dl[(size_t)((t-5)*64 + b)*16 + lane];
    }
    if (t - 2 >= 0) BSTEP(p2, d2, t-2);
    if (t - 6 >= 0 && lane < 16){
      p2 = psi[(size_t)((t-5)*64 + b)*16 + lane]; d2 = dl[(size_t)((t-6)*64 + b)*16 + lane];
    }
    if (t - 3 >= 0) BSTEP(p3, d3, t-3);
    if (t - 7 >= 0 && lane < 16){
      p3 = psi[(size_t)((t-6)*64 + b)*16 + lane]; d3 = dl[(size_t)((t-7)*64 + b)*16 + lane];
    }
  }
#undef BSTEP
  if (lane == 0) dout[32768 + b] = score;
}

// ---------------- launcher ----------------
extern "C" void kernel_launch(void* const* d_in, const int* in_sizes, int n_in,
                              void* d_out, int out_size, void* d_ws, size_t ws_size,
                              hipStream_t stream)
{
  (void)in_sizes; (void)n_in; (void)out_size;
  if (ws_size < REQUIRED) return;

  const int*   X    = (const int*)d_in[0];
  const float* lm   = (const float*)d_in[1];
  const int*   tg   = (const int*)d_in[2];
  const int*   ch   = (const int*)d_in[3];
  const float* etab = (const float*)d_in[4];
  const float* ttab = (const float*)d_in[5];
  const float* ctab = (const float*)d_in[6];
  const float* cw   = (const float*)d_in[7];
  const float* cb   = (const float*)d_in[8];
  const float* wihf = (const float*)d_in[9];
  const float* whhf = (const float*)d_in[10];
  const float* bihf = (const float*)d_in[11];
  const float* bhhf = (const float*)d_in[12];
  const float* wihb = (const float*)d_in[13];
  const float* whhb = (const float*)d_in[14];
  const float* bihb = (const float*)d_in[15];
  const float* bhhb = (const float*)d_in[16];
  const float* fcw  = (const float*)d_in[17];
  const float* fcb  = (const float*)d_in[18];
  const float* Am   = (const float*)d_in[19];
  const float* wdp  = (const float*)d_in[20];

  char* ws = (char*)d_ws;
  u16*   gi   = (u16*)(ws + OFF_GI);
  u16*   feat = (u16*)(ws + OFF_B);
  u16*   hcat = (u16*)(ws + OFF_B);
  u16*   wih  = (u16*)(ws + OFF_WIH);
  s8*    wq   = (s8*)(ws + OFF_WQ);
  float* sc2  = (float*)(ws + OFF_SC);
  float* Pg   = (float*)(ws + OFF_P);
  float* dlt  = (float*)(ws + OFF_DL);
  u8*    psi  = (u8*)(ws + OFF_PSI);
  float* bias = (float*)(ws + OFF_BIAS);
  float* wfc  = (float*)(ws + OFF_WFC);
  float* dout = (float*)d_out;

  k0_pack<<<2048, 256, 0, stream>>>(wihf, wihb, wih);
  k0q<<<512, 256, 0, stream>>>(whhf, whhb, wq, sc2);
  k0_misc<<<1, 256, 0, stream>>>(bihf, bhhf, bihb, bhhb, fcw, wdp, bias, wfc);
  k1_feat<<<dim3(128, 64), 256, 0, stream>>>(X, tg, ch, etab, ttab, ctab, cw, cb, feat);
  k2_gemm<<<dim3(16, 256), 256, 0, stream>>>(feat, wih, bias, gi);
  k3_lstm<<<64, 512, 0, stream>>>(wq, sc2, gi, hcat);
  k4_fc<<<512, 256, 0, stream>>>(hcat, fcw, fcb, lm, wfc, Pg);
  k5_vit<<<64, 64, 0, stream>>>(Pg, Am, dout, dlt, psi);
}

// Round 10
// 1259.824 us; speedup vs baseline: 1.1047x; 1.1047x over previous
//
#include <hip/hip_runtime.h>

// BiLSTM-CRF on MI355X. Round 10: K3 = round-8 spread-cell structure but with
// WAVE-LOCAL cell ownership -> xbuf exchange is intra-wave (lgkmcnt only, no
// barrier); single cross-wave barrier per step (Hs). K2 keeps [dir][s][b][j][g].

#define DEV __device__ __forceinline__
typedef unsigned short u16;
typedef unsigned int   u32;
typedef unsigned char  u8;
typedef signed char    s8;
using short8  = __attribute__((ext_vector_type(8))) short;
using ushort4v= __attribute__((ext_vector_type(4))) unsigned short;
using f32x4   = __attribute__((ext_vector_type(4))) float;
using int4v   = __attribute__((ext_vector_type(4))) int;

DEV float bf2f(u16 u){ union{u32 i; float f;} v; v.i = ((u32)u)<<16; return v.f; }
DEV u16 f2bf(float f){ u32 x = __float_as_uint(f); return (u16)((x + 0x7fffu + ((x>>16)&1u)) >> 16); }
DEV float sigf(float x){ return __builtin_amdgcn_rcpf(1.f + __expf(-x)); }
DEV float tanh_f(float x){ return 1.f - 2.f*__builtin_amdgcn_rcpf(__expf(2.f*x) + 1.f); }

typedef __attribute__((address_space(1))) const u32 GU;
typedef __attribute__((address_space(3))) u32 LU;
DEV void gld_lds16(const void* g, void* l){
  __builtin_amdgcn_global_load_lds((GU*)g, (LU*)l, 16, 0, 0);
}
// LDS-only barrier: no vmcnt drain
DEV void bar_l(){
  __builtin_amdgcn_sched_barrier(0);
  asm volatile("s_waitcnt lgkmcnt(0)" ::: "memory");
  __builtin_amdgcn_s_barrier();
  __builtin_amdgcn_sched_barrier(0);
}
// intra-wave LDS RAW fence (no s_barrier)
DEV void lgkm0(){
  __builtin_amdgcn_sched_barrier(0);
  asm volatile("s_waitcnt lgkmcnt(0)" ::: "memory");
  __builtin_amdgcn_sched_barrier(0);
}

// ---------------- ws layout (aliased; total ~170MB) ----------------
static const size_t OFF_GI   = 0;
static const size_t OFF_P    = 0;
static const size_t OFF_DL   = OFF_P  + (size_t)32768*16*4;
static const size_t OFF_PSI  = OFF_DL + (size_t)32768*16*4;
static const size_t OFF_B    = (size_t)134217728;
static const size_t OFF_WIH  = OFF_B    + (size_t)33554432;
static const size_t OFF_WQ   = OFF_WIH  + (size_t)1703936;   // 512KB i8 frags
static const size_t OFF_SC   = OFF_WQ   + (size_t)524288;    // 8KB scales
static const size_t OFF_BIAS = OFF_SC   + 8192;
static const size_t OFF_WFC  = OFF_BIAS + 8192;
static const size_t REQUIRED = OFF_WFC  + 256;

// ---------------- K0: pack W_ih (f32 -> bf16 [2048][416]) ----------------
__global__ void k0_pack(const float* __restrict__ wihf, const float* __restrict__ wihb,
                        u16* __restrict__ wih)
{
  int n = blockIdx.x, tid = threadIdx.x;
  const float* src = (n < 1024) ? (wihf + (size_t)n*400) : (wihb + (size_t)(n-1024)*400);
  u32* dst = (u32*)(wih + (size_t)n*416);
  if (tid < 208){
    int j = tid*2;
    u32 v = 0u;
    if (j < 400){
      float2 f = *(const float2*)(src + j);
      v = (u32)f2bf(f.x) | ((u32)f2bf(f.y) << 16);
    }
    dst[tid] = v;
  }
}

// ---------------- K0q: quantize W_hh rows to i8 MFMA fragments ----------------
__global__ __launch_bounds__(256) void k0q(
    const float* __restrict__ whhf, const float* __restrict__ whhb,
    s8* __restrict__ wq, float* __restrict__ sc2)
{
  const int row = blockIdx.x*4 + (threadIdx.x >> 6);
  const int lane = threadIdx.x & 63;
  const float* src = (row < 1024) ? (whhf + (size_t)row*256)
                                  : (whhb + (size_t)(row-1024)*256);
  f32x4 v = *(const f32x4*)(src + lane*4);
  float m = fmaxf(fmaxf(fabsf(v[0]), fabsf(v[1])), fmaxf(fabsf(v[2]), fabsf(v[3])));
  #pragma unroll
  for (int d = 1; d < 64; d <<= 1) m = fmaxf(m, __shfl_xor(m, d, 64));
  float inv = 127.f / (m + 1e-30f);
  u32 pack = 0;
  #pragma unroll
  for (int e = 0; e < 4; e++){
    int q = (int)rintf(v[e]*inv);
    q = q > 127 ? 127 : (q < -127 ? -127 : q);
    pack |= ((u32)(u8)(s8)q) << (8*e);
  }
  const int dir = row >> 10, n = row & 1023;
  const int g = n >> 8, j = n & 255, w2 = j >> 4, lr2 = j & 15;
  const int kk = lane >> 4, lq2 = (lane >> 2) & 3, e4 = lane & 3;
  u32* wq32 = (u32*)wq;
  wq32[dir*65536 + (((g*16 + w2)*4 + kk)*64 + lq2*16 + lr2)*4 + e4] = pack;
  if (lane == 0) sc2[row] = m * (1.f/16129.f);
}

// ---------------- K0b: bias sums (fp32) + wfc = fc_w @ wd (parallel) ----------------
__global__ void k0_misc(const float* bihf, const float* bhhf, const float* bihb, const float* bhhb,
                        const float* fcw, const float* wdp, float* bias, float* wfc)
{
  __shared__ float red[256];
  int tid = threadIdx.x;
  for (int n = tid; n < 2048; n += 256){
    bias[n] = (n < 1024) ? (bihf[n] + bhhf[n]) : (bihb[n-1024] + bhhb[n-1024]);
  }
  const int cur = tid & 15, part = tid >> 4;
  float s = 0.f;
  for (int k = part*32; k < part*32 + 32; k++) s += fcw[cur*512 + k] * wdp[k];
  red[tid] = s;
  __syncthreads();
  if (tid < 16){
    float t = 0.f;
    #pragma unroll
    for (int p = 0; p < 16; p++) t += red[p*16 + tid];
    wfc[tid] = t;
  }
}

// ---------------- K1: features -> feat[s*64+b][416] bf16 ----------------
__global__ __launch_bounds__(256) void k1_feat(
    const int* __restrict__ X, const int* __restrict__ tg, const int* __restrict__ ch,
    const float* __restrict__ etab, const float* __restrict__ ttab, const float* __restrict__ ctab,
    const float* __restrict__ cw, const float* __restrict__ cb, u16* __restrict__ feat)
{
  const int sb = blockIdx.x, b = blockIdx.y, tid = threadIdx.x;
  __shared__ float ce_s[66*60];
  __shared__ float w_s[150*52];
  for (int i = tid; i < 600; i += 256){
    int wl = i/150, j = i - wl*150;
    int s = sb*4 + wl;
    int idx = X[b*512 + s];
    float2 f = *(const float2*)(etab + (size_t)idx*300 + j*2);
    *(u32*)(feat + (size_t)(s*64 + b)*416 + j*2) = (u32)f2bf(f.x) | ((u32)f2bf(f.y) << 16);
  }
  for (int i = tid; i < 100; i += 256){
    int wl = i/25, j = i - wl*25;
    int s = sb*4 + wl;
    int idx = tg[b*512 + s];
    float2 f = *(const float2*)(ttab + (size_t)idx*50 + j*2);
    *(u32*)(feat + (size_t)(s*64 + b)*416 + 300 + j*2) = (u32)f2bf(f.x) | ((u32)f2bf(f.y) << 16);
  }
  if (tid < 32){
    int wl = tid>>3, j = tid&7;
    int s = sb*4 + wl;
    *(u32*)(feat + (size_t)(s*64 + b)*416 + 400 + j*2) = 0u;
  }
  for (int i = tid; i < 3300; i += 256){
    int qq = i/50, ce = i - qq*50;
    int p = sb*64 - 1 + qq;
    float v = 0.f;
    if (p >= 0 && p < 8192){
      int ci = ch[b*8192 + p];
      v = ctab[ci*50 + ce];
    }
    ce_s[qq*60 + ce] = v;
  }
  for (int i = tid; i < 7500; i += 256){
    int cc = i/150, r2 = i - cc*150;
    int ce = r2/3, dc = r2 - ce*3;
    w_s[(cc*3 + dc)*52 + ce] = cw[i];
  }
  __syncthreads();
  const int li = tid & 15, jg = tid >> 4;
  float acc[4][3];
  #pragma unroll
  for (int k=0;k<4;k++){ acc[k][0]=0.f; acc[k][1]=0.f; acc[k][2]=0.f; }
  #pragma unroll
  for (int dc = 0; dc < 3; dc++){
    for (int ceb = 0; ceb < 48; ceb += 4){
      f32x4 w0 = *(const f32x4*)&w_s[((3*jg+0)*3 + dc)*52 + ceb];
      f32x4 w1 = *(const f32x4*)&w_s[((3*jg+1)*3 + dc)*52 + ceb];
      f32x4 w2 = *(const f32x4*)&w_s[((3*jg+2)*3 + dc)*52 + ceb];
      #pragma unroll
      for (int k = 0; k < 4; k++){
        f32x4 cv = *(const f32x4*)&ce_s[(16*k + li + dc)*60 + ceb];
        #pragma unroll
        for (int e = 0; e < 4; e++){
          acc[k][0] += cv[e]*w0[e];
          acc[k][1] += cv[e]*w1[e];
          acc[k][2] += cv[e]*w2[e];
        }
      }
    }
    float w0a = w_s[((3*jg+0)*3+dc)*52 + 48], w0b = w_s[((3*jg+0)*3+dc)*52 + 49];
    float w1a = w_s[((3*jg+1)*3+dc)*52 + 48], w1b = w_s[((3*jg+1)*3+dc)*52 + 49];
    float w2a = w_s[((3*jg+2)*3+dc)*52 + 48], w2b = w_s[((3*jg+2)*3+dc)*52 + 49];
    #pragma unroll
    for (int k = 0; k < 4; k++){
      float ca = ce_s[(16*k + li + dc)*60 + 48];
      float cb2 = ce_s[(16*k + li + dc)*60 + 49];
      acc[k][0] += ca*w0a + cb2*w0b;
      acc[k][1] += ca*w1a + cb2*w1b;
      acc[k][2] += ca*w2a + cb2*w2b;
    }
  }
  #pragma unroll
  for (int m = 1; m < 16; m <<= 1)
    #pragma unroll
    for (int k=0;k<4;k++)
      #pragma unroll
      for (int c=0;c<3;c++)
        acc[k][c] = fmaxf(acc[k][c], __shfl_xor(acc[k][c], m, 64));
  if (li == 0){
    #pragma unroll
    for (int k=0;k<4;k++)
      #pragma unroll
      for (int c=0;c<3;c++){
        int cc = 3*jg + c;
        int s = sb*4 + k;
        feat[(size_t)(s*64 + b)*416 + 350 + cc] = f2bf(acc[k][c] + cb[cc]);
      }
  }
  if (tid < 128){
    int pl = tid & 63, cc = 48 + (tid >> 6);
    float a2 = 0.f;
    #pragma unroll
    for (int dc = 0; dc < 3; dc++){
      for (int ceb = 0; ceb < 48; ceb += 4){
        f32x4 wv = *(const f32x4*)&w_s[(cc*3 + dc)*52 + ceb];
        f32x4 cv = *(const f32x4*)&ce_s[(pl + dc)*60 + ceb];
        a2 += cv[0]*wv[0] + cv[1]*wv[1] + cv[2]*wv[2] + cv[3]*wv[3];
      }
      a2 += ce_s[(pl+dc)*60 + 48]*w_s[(cc*3+dc)*52 + 48]
          + ce_s[(pl+dc)*60 + 49]*w_s[(cc*3+dc)*52 + 49];
    }
    #pragma unroll
    for (int m = 1; m < 16; m <<= 1) a2 = fmaxf(a2, __shfl_xor(a2, m, 64));
    if ((tid & 15) == 0){
      int s = sb*4 + ((tid & 63) >> 4);
      feat[(size_t)(s*64 + b)*416 + 350 + cc] = f2bf(a2 + cb[cc]);
    }
  }
}

// ---------------- K2: gi = bf16(feat @ wih^T + bias), layout [dir][s][b][j][g] ----------------
__global__ __launch_bounds__(256) void k2_gemm(
    const u16* __restrict__ featp, const u16* __restrict__ wihp,
    const float* __restrict__ bias, u16* __restrict__ gi)
{
  const int m0 = blockIdx.y*128, n0 = blockIdx.x*128;
  const int tid = threadIdx.x, wv = tid>>6, lane = tid&63;
  const int lr = lane & 15, lq = lane >> 4;
  const int wm = (wv>>1)*64, wn = (wv&1)*64;
  __shared__ u16 As[4096], Bs[4096];
  f32x4 acc[4][4];
  #pragma unroll
  for (int a=0;a<4;a++)
    #pragma unroll
    for (int c=0;c<4;c++) acc[a][c] = (f32x4){0.f,0.f,0.f,0.f};
  for (int k0 = 0; k0 < 416; k0 += 32){
    __syncthreads();
    #pragma unroll
    for (int i = 0; i < 2; i++){
      int c = i*4 + wv;
      gld_lds16(featp + (size_t)(m0 + c*16 + (lane>>2))*416 + k0 + (lane&3)*8, &As[c*512]);
      gld_lds16(wihp  + (size_t)(n0 + c*16 + (lane>>2))*416 + k0 + (lane&3)*8, &Bs[c*512]);
    }
    __syncthreads();
    short8 af[4], bfr[4];
    #pragma unroll
    for (int mt=0; mt<4; mt++) af[mt]  = *(const short8*)(As + (wm + mt*16 + lr)*32 + lq*8);
    #pragma unroll
    for (int nt=0; nt<4; nt++) bfr[nt] = *(const short8*)(Bs + (wn + nt*16 + lr)*32 + lq*8);
    #pragma unroll
    for (int mt=0; mt<4; mt++)
      #pragma unroll
      for (int nt=0; nt<4; nt++)
        acc[mt][nt] = __builtin_amdgcn_mfma_f32_16x16x32_bf16(af[mt], bfr[nt], acc[mt][nt], 0,0,0);
  }
  #pragma unroll
  for (int nt=0; nt<4; nt++){
    const int n = n0 + wn + nt*16 + lr;
    const float bv = bias[n];
    const int dirn = n >> 10, g = (n >> 8) & 3, j = n & 255;
    #pragma unroll
    for (int mt=0; mt<4; mt++)
      #pragma unroll
      for (int r=0; r<4; r++){
        const int m = m0 + wm + mt*16 + lq*4 + r;
        const int s = m >> 6, b = m & 63;
        gi[((size_t)((dirn*512 + s)*64 + b) << 10) + (j << 2) + g]
            = f2bf(acc[mt][nt][r] + bv);
      }
  }
}

// ---------------- K3: recurrent BiLSTM — wave-local cells, 1 barrier/step ----------------
// 64 blocks x 512 thr. dir = blk>>5, batch rows bb=(blk&31)*2. Wave w owns
// j-slices 2w,2w+1 (all 4 gates). Lane l owns cell (r=l>>5, j=2w*16+(l&31)):
// acc -> xbuf is INTRA-wave (lgkmcnt only); single cross-wave barrier (Hs).
__global__ __launch_bounds__(512, 2) void k3_lstm(
    const s8* __restrict__ wq, const float* __restrict__ sc2,
    const u16* __restrict__ gi, u16* __restrict__ hcat)
{
  const int dir = blockIdx.x >> 5;
  const int bb  = (blockIdx.x & 31) * 2;
  const int tid = threadIdx.x;
  const int w = tid >> 6, lane = tid & 63;
  const int lr = lane & 15, lq = lane >> 4;

  __shared__ s8 Hs[2][4096];        // h dbuf [16 rows (2 valid)][256], col^=(b<<4)
  __shared__ float xbuf[8][2][32][4]; // per-wave exchange [w][r][jloc][g], 8KB

  const s8* wqd = wq + dir*262144;
  int4v bq[2][4][4];
  #pragma unroll
  for (int sl = 0; sl < 2; sl++)
    #pragma unroll
    for (int g = 0; g < 4; g++)
      #pragma unroll
      for (int kk = 0; kk < 4; kk++)
        bq[sl][g][kk] = *(const int4v*)(wqd + (((((g*16 + 2*w + sl)*4 + kk)*64) + lane) << 4));

  // cell identity (wave-local): lane owns (r_own, j_own)
  const int r_own = lane >> 5;
  const int jloc  = lane & 31;
  const int j_own = 2*w*16 + jloc;

  float scl[4];
  #pragma unroll
  for (int g = 0; g < 4; g++) scl[g] = sc2[dir*1024 + g*256 + j_own];

  *(uint2*)&Hs[0][tid*8] = (uint2){0u,0u};
  *(uint2*)&Hs[1][tid*8] = (uint2){0u,0u};

  float cst = 0.f;
  const ptrdiff_t dstep = dir ? -(ptrdiff_t)65536 : (ptrdiff_t)65536;  // +-64*1024 u16
  const u16* gp = gi + ((size_t)((dir*512 + (dir ? 511 : 0))*64 + bb + r_own) << 10) + j_own*4;
  ushort4v gc, g1, g2;
  gc = *(const ushort4v*)gp;
  g1 = *(const ushort4v*)(gp + dstep);
  const u16* gpref = gp + dstep;
  __syncthreads();

  #pragma unroll 1
  for (int t = 0; t < 512; t++){
    const int s = dir ? (511 - t) : t;
    // prefetch step t+2's gate inputs
    if (t + 2 < 512) gpref += dstep;
    g2 = *(const ushort4v*)gpref;
    // MFMA phase (weights in VGPR, h from LDS)
    const s8* hb = Hs[t & 1];
    int4v aq[4];
    #pragma unroll
    for (int kk = 0; kk < 4; kk++)
      aq[kk] = *(const int4v*)(hb + lr*256 + ((kk*64 + lq*16) ^ (lr << 4)));
    int4v acc[2][4];
    #pragma unroll
    for (int sl = 0; sl < 2; sl++)
      #pragma unroll
      for (int g = 0; g < 4; g++) acc[sl][g] = (int4v){0,0,0,0};
    #pragma unroll
    for (int kk = 0; kk < 4; kk++)
      #pragma unroll
      for (int sl = 0; sl < 2; sl++)
        #pragma unroll
        for (int g = 0; g < 4; g++)
          acc[sl][g] = __builtin_amdgcn_mfma_i32_16x16x64_i8(aq[kk], bq[sl][g][kk], acc[sl][g], 0,0,0);
    // intra-wave redistribute: owner lanes (lq==0, C rows 0,1) -> xbuf[w]
    if (lq == 0){
      #pragma unroll
      for (int sl = 0; sl < 2; sl++)
        #pragma unroll
        for (int r = 0; r < 2; r++){
          f32x4 v = (f32x4){(float)acc[sl][0][r], (float)acc[sl][1][r],
                            (float)acc[sl][2][r], (float)acc[sl][3][r]};
          *(f32x4*)&xbuf[w][r][sl*16 + lr][0] = v;
        }
    }
    lgkm0();                     // intra-wave RAW fence; no s_barrier
    f32x4 p = *(const f32x4*)&xbuf[w][r_own][jloc][0];
    // cell update: 1 cell per lane
    float g4[4];
    #pragma unroll
    for (int g = 0; g < 4; g++) g4[g] = bf2f((u16)gc[g]) + p[g]*scl[g];
    float iv = sigf(g4[0]), fv = sigf(g4[1]);
    float gg = tanh_f(g4[2]), ov = sigf(g4[3]);
    float c = fv*cst + iv*gg;
    cst = c;
    float h = ov * tanh_f(c);
    hcat[(size_t)(s*64 + bb + r_own)*512 + dir*256 + j_own] = f2bf(h);
    Hs[(t + 1) & 1][r_own*256 + (j_own ^ (r_own << 4))] = (s8)(int)rintf(h * 127.f);
    gc = g1; g1 = g2;
    bar_l();                     // single cross-wave barrier: Hs[t+1] visible
  }
}

// ---------------- K4: P = Hcat @ fc_w^T + fc_b + lm*wfc  [32768 x 16] fp32 ----------------
__global__ __launch_bounds__(256) void k4_fc(
    const u16* __restrict__ hcat, const float* __restrict__ fcw, const float* __restrict__ fcb,
    const float* __restrict__ lmp, const float* __restrict__ wfc, float* __restrict__ Pout)
{
  const int wv = threadIdx.x >> 6, lane = threadIdx.x & 63;
  const int lr = lane & 15, lq = lane >> 4;
  const int mt = blockIdx.x*4 + wv;
  short8 bfr[16];
  #pragma unroll
  for (int kk = 0; kk < 16; kk++){
    const float* wr = fcw + (size_t)lr*512 + kk*32 + lq*8;
    f32x4 w0 = *(const f32x4*)wr;
    f32x4 w1 = *(const f32x4*)(wr + 4);
    short8 sv;
    #pragma unroll
    for (int e = 0; e < 4; e++){ sv[e] = (short)f2bf(w0[e]); sv[4+e] = (short)f2bf(w1[e]); }
    bfr[kk] = sv;
  }
  f32x4 acc = (f32x4){0.f,0.f,0.f,0.f};
  #pragma unroll
  for (int kk = 0; kk < 16; kk++){
    short8 af = *(const short8*)(hcat + (size_t)(mt*16 + lr)*512 + kk*32 + lq*8);
    acc = __builtin_amdgcn_mfma_f32_16x16x32_bf16(af, bfr[kk], acc, 0,0,0);
  }
  const int cur = lr;
  float fb = fcb[cur];
  float wf = wfc[cur];
  #pragma unroll
  for (int r = 0; r < 4; r++){
    int m = mt*16 + lq*4 + r;
    int b = m & 63, s = m >> 6;
    float lmv = lmp[b*512 + s];
    Pout[(size_t)m*16 + cur] = acc[r] + fb + lmv*wf;
  }
}

// ---------------- K5: Viterbi — de-scratched (static regs, 4x unroll) ----------------
__global__ __launch_bounds__(64) void k5_vit(
    const float* __restrict__ Pg, const float* __restrict__ Am,
    float* __restrict__ dout, float* __restrict__ dl, u8* __restrict__ psi)
{
  const int b = blockIdx.x, lane = threadIdx.x;
  const int cur = lane >> 2, q = lane & 3;
  float Ar[4];
  #pragma unroll
  for (int r = 0; r < 4; r++) Ar[r] = Am[(4*q + r)*16 + cur];
  float val = Pg[(size_t)b*16 + cur];
  if (q == 0) dl[(size_t)b*16 + cur] = val;

#define FSTEP(X, S) { \
    float best = -3.0e38f; int bi = 0; \
    _Pragma("unroll") \
    for (int r = 0; r < 4; r++){ \
      float dp = __shfl(val, (4*q + r)*4, 64); \
      float sc = (dp + Ar[r]) + (X); \
      if (sc > best){ best = sc; bi = 4*q + r; } \
    } \
    { float ov = __shfl_xor(best, 1, 64); int oi = __shfl_xor(bi, 1, 64); \
      if (ov > best || (ov == best && oi < bi)){ best = ov; bi = oi; } } \
    { float ov = __shfl_xor(best, 2, 64); int oi = __shfl_xor(bi, 2, 64); \
      if (ov > best || (ov == best && oi < bi)){ best = ov; bi = oi; } } \
    val = best; \
    if (q == 0){ \
      dl[(size_t)((S)*64 + b)*16 + cur] = best; \
      psi[(size_t)((S)*64 + b)*16 + cur] = (u8)bi; \
    } }

  float x0 = Pg[(size_t)(1*64 + b)*16 + cur];
  float x1 = Pg[(size_t)(2*64 + b)*16 + cur];
  float x2 = Pg[(size_t)(3*64 + b)*16 + cur];
  float x3 = Pg[(size_t)(4*64 + b)*16 + cur];
  for (int s = 1; s < 512; s += 4){
    FSTEP(x0, s);
    if (s + 4 < 512) x0 = Pg[(size_t)((s+4)*64 + b)*16 + cur];
    if (s + 1 < 512) FSTEP(x1, s+1);
    if (s + 5 < 512) x1 = Pg[(size_t)((s+5)*64 + b)*16 + cur];
    if (s + 2 < 512) FSTEP(x2, s+2);
    if (s + 6 < 512) x2 = Pg[(size_t)((s+6)*64 + b)*16 + cur];
    if (s + 3 < 512) FSTEP(x3, s+3);
    if (s + 7 < 512) x3 = Pg[(size_t)((s+7)*64 + b)*16 + cur];
  }
#undef FSTEP

  float bv = val; int bix = cur;
  #pragma unroll
  for (int m = 1; m < 64; m <<= 1){
    float ov = __shfl_xor(bv, m, 64);
    int   oi = __shfl_xor(bix, m, 64);
    if (ov > bv || (ov == bv && oi < bix)){ bv = ov; bix = oi; }
  }
  int tag = bix;
  float score = bv;
  if (lane == 0) dout[b*512 + 511] = (float)tag;

#define BSTEP(PV, DV, T) { \
    int prev = __shfl((PV), tag, 64); \
    score += __shfl((DV), prev, 64); \
    if (lane == 0) dout[b*512 + (T)] = (float)prev; \
    tag = prev; }

  int   p0 = 0, p1 = 0, p2 = 0, p3 = 0;
  float d0 = 0.f, d1 = 0.f, d2 = 0.f, d3 = 0.f;
  if (lane < 16){
    p0 = psi[(size_t)(511*64 + b)*16 + lane]; d0 = dl[(size_t)(510*64 + b)*16 + lane];
    p1 = psi[(size_t)(510*64 + b)*16 + lane]; d1 = dl[(size_t)(509*64 + b)*16 + lane];
    p2 = psi[(size_t)(509*64 + b)*16 + lane]; d2 = dl[(size_t)(508*64 + b)*16 + lane];
    p3 = psi[(size_t)(508*64 + b)*16 + lane]; d3 = dl[(size_t)(507*64 + b)*16 + lane];
  }
  for (int t = 510; t >= 0; t -= 4){
    BSTEP(p0, d0, t);
    if (t - 4 >= 0 && lane < 16){
      p0 = psi[(size_t)((t-3)*64 + b)*16 + lane]; d0 = dl[(size_t)((t-4)*64 + b)*16 + lane];
    }
    if (t - 1 >= 0) BSTEP(p1, d1, t-1);
    if (t - 5 >= 0 && lane < 16){
      p1 = psi[(size_t)((t-4)*64 + b)*16 + lane]; d1 = dl[(size_t)((t-5)*64 + b)*16 + lane];
    }
    if (t - 2 >= 0) BSTEP(p2, d2, t-2);
    if (t - 6 >= 0 && lane < 16){
      p2 = psi[(size_t)((t-5)*64 + b)*16 + lane]; d2 = dl[(size_t)((t-6)*64 + b)*16 + lane];
    }
    if (t - 3 >= 0) BSTEP(p3, d3, t-3);
    if (t - 7 >= 0 && lane < 16){
      p3 = psi[(size_t)((t-6)*64 + b)*16 + lane]; d3 = dl[(size_t)((t-7)*64 + b)*16 + lane];
    }
  }
#undef BSTEP
  if (lane == 0) dout[32768 + b] = score;
}

// ---------------- launcher ----------------
extern "C" void kernel_launch(void* const* d_in, const int* in_sizes, int n_in,
                              void* d_out, int out_size, void* d_ws, size_t ws_size,
                              hipStream_t stream)
{
  (void)in_sizes; (void)n_in; (void)out_size;
  if (ws_size < REQUIRED) return;

  const int*   X    = (const int*)d_in[0];
  const float* lm   = (const float*)d_in[1];
  const int*   tg   = (const int*)d_in[2];
  const int*   ch   = (const int*)d_in[3];
  const float* etab = (const float*)d_in[4];
  const float* ttab = (const float*)d_in[5];
  const float* ctab = (const float*)d_in[6];
  const float* cw   = (const float*)d_in[7];
  const float* cb   = (const float*)d_in[8];
  const float* wihf = (const float*)d_in[9];
  const float* whhf = (const float*)d_in[10];
  const float* bihf = (const float*)d_in[11];
  const float* bhhf = (const float*)d_in[12];
  const float* wihb = (const float*)d_in[13];
  const float* whhb = (const float*)d_in[14];
  const float* bihb = (const float*)d_in[15];
  const float* bhhb = (const float*)d_in[16];
  const float* fcw  = (const float*)d_in[17];
  const float* fcb  = (const float*)d_in[18];
  const float* Am   = (const float*)d_in[19];
  const float* wdp  = (const float*)d_in[20];

  char* ws = (char*)d_ws;
  u16*   gi   = (u16*)(ws + OFF_GI);
  u16*   feat = (u16*)(ws + OFF_B);
  u16*   hcat = (u16*)(ws + OFF_B);
  u16*   wih  = (u16*)(ws + OFF_WIH);
  s8*    wq   = (s8*)(ws + OFF_WQ);
  float* sc2  = (float*)(ws + OFF_SC);
  float* Pg   = (float*)(ws + OFF_P);
  float* dlt  = (float*)(ws + OFF_DL);
  u8*    psi  = (u8*)(ws + OFF_PSI);
  float* bias = (float*)(ws + OFF_BIAS);
  float* wfc  = (float*)(ws + OFF_WFC);
  float* dout = (float*)d_out;

  k0_pack<<<2048, 256, 0, stream>>>(wihf, wihb, wih);
  k0q<<<512, 256, 0, stream>>>(whhf, whhb, wq, sc2);
  k0_misc<<<1, 256, 0, stream>>>(bihf, bhhf, bihb, bhhb, fcw, wdp, bias, wfc);
  k1_feat<<<dim3(128, 64), 256, 0, stream>>>(X, tg, ch, etab, ttab, ctab, cw, cb, feat);
  k2_gemm<<<dim3(16, 256), 256, 0, stream>>>(feat, wih, bias, gi);
  k3_lstm<<<64, 512, 0, stream>>>(wq, sc2, gi, hcat);
  k4_fc<<<512, 256, 0, stream>>>(hcat, fcw, fcb, lm, wfc, Pg);
  k5_vit<<<64, 64, 0, stream>>>(Pg, Am, dout, dlt, psi);
}

// Round 11
// 1194.372 us; speedup vs baseline: 1.1653x; 1.0548x over previous
//
#include <hip/hip_runtime.h>

// BiLSTM-CRF on MI355X. Round 11: restore round-8 K2 (coalesced) + K3 (500us);
// K1 restructured to 1024 blocks x 8 sb-tiles (weights staged once); k0q+k0_misc merged.

#define DEV __device__ __forceinline__
typedef unsigned short u16;
typedef unsigned int   u32;
typedef unsigned char  u8;
typedef signed char    s8;
using short8  = __attribute__((ext_vector_type(8))) short;
using f32x4   = __attribute__((ext_vector_type(4))) float;
using int4v   = __attribute__((ext_vector_type(4))) int;

DEV float bf2f(u16 u){ union{u32 i; float f;} v; v.i = ((u32)u)<<16; return v.f; }
DEV u16 f2bf(float f){ u32 x = __float_as_uint(f); return (u16)((x + 0x7fffu + ((x>>16)&1u)) >> 16); }
DEV float sigf(float x){ return __builtin_amdgcn_rcpf(1.f + __expf(-x)); }
DEV float tanh_f(float x){ return 1.f - 2.f*__builtin_amdgcn_rcpf(__expf(2.f*x) + 1.f); }

typedef __attribute__((address_space(1))) const u32 GU;
typedef __attribute__((address_space(3))) u32 LU;
DEV void gld_lds16(const void* g, void* l){
  __builtin_amdgcn_global_load_lds((GU*)g, (LU*)l, 16, 0, 0);
}
DEV void bar_l(){
  __builtin_amdgcn_sched_barrier(0);
  asm volatile("s_waitcnt lgkmcnt(0)" ::: "memory");
  __builtin_amdgcn_s_barrier();
  __builtin_amdgcn_sched_barrier(0);
}

// ---------------- ws layout (aliased; total ~170MB) ----------------
static const size_t OFF_GI   = 0;
static const size_t OFF_P    = 0;
static const size_t OFF_DL   = OFF_P  + (size_t)32768*16*4;
static const size_t OFF_PSI  = OFF_DL + (size_t)32768*16*4;
static const size_t OFF_B    = (size_t)134217728;
static const size_t OFF_WIH  = OFF_B    + (size_t)33554432;
static const size_t OFF_WQ   = OFF_WIH  + (size_t)1703936;   // 512KB i8 frags
static const size_t OFF_SC   = OFF_WQ   + (size_t)524288;    // 8KB scales
static const size_t OFF_BIAS = OFF_SC   + 8192;
static const size_t OFF_WFC  = OFF_BIAS + 8192;
static const size_t REQUIRED = OFF_WFC  + 256;

// ---------------- K0: pack W_ih (f32 -> bf16 [2048][416]) ----------------
__global__ void k0_pack(const float* __restrict__ wihf, const float* __restrict__ wihb,
                        u16* __restrict__ wih)
{
  int n = blockIdx.x, tid = threadIdx.x;
  const float* src = (n < 1024) ? (wihf + (size_t)n*400) : (wihb + (size_t)(n-1024)*400);
  u32* dst = (u32*)(wih + (size_t)n*416);
  if (tid < 208){
    int j = tid*2;
    u32 v = 0u;
    if (j < 400){
      float2 f = *(const float2*)(src + j);
      v = (u32)f2bf(f.x) | ((u32)f2bf(f.y) << 16);
    }
    dst[tid] = v;
  }
}

// ---------------- K0qm: quantize W_hh (blocks 0..511) + bias/wfc (block 512) ----------------
__global__ __launch_bounds__(256) void k0qm(
    const float* __restrict__ whhf, const float* __restrict__ whhb,
    s8* __restrict__ wq, float* __restrict__ sc2,
    const float* bihf, const float* bhhf, const float* bihb, const float* bhhb,
    const float* fcw, const float* wdp, float* bias, float* wfc)
{
  __shared__ float red[256];
  const int tid = threadIdx.x;
  if (blockIdx.x == 512){
    for (int n = tid; n < 2048; n += 256){
      bias[n] = (n < 1024) ? (bihf[n] + bhhf[n]) : (bihb[n-1024] + bhhb[n-1024]);
    }
    const int cur = tid & 15, part = tid >> 4;
    float s = 0.f;
    for (int k = part*32; k < part*32 + 32; k++) s += fcw[cur*512 + k] * wdp[k];
    red[tid] = s;
    __syncthreads();
    if (tid < 16){
      float t = 0.f;
      #pragma unroll
      for (int p = 0; p < 16; p++) t += red[p*16 + tid];
      wfc[tid] = t;
    }
    return;
  }
  const int row = blockIdx.x*4 + (tid >> 6);
  const int lane = tid & 63;
  const float* src = (row < 1024) ? (whhf + (size_t)row*256)
                                  : (whhb + (size_t)(row-1024)*256);
  f32x4 v = *(const f32x4*)(src + lane*4);
  float m = fmaxf(fmaxf(fabsf(v[0]), fabsf(v[1])), fmaxf(fabsf(v[2]), fabsf(v[3])));
  #pragma unroll
  for (int d = 1; d < 64; d <<= 1) m = fmaxf(m, __shfl_xor(m, d, 64));
  float inv = 127.f / (m + 1e-30f);
  u32 pack = 0;
  #pragma unroll
  for (int e = 0; e < 4; e++){
    int q = (int)rintf(v[e]*inv);
    q = q > 127 ? 127 : (q < -127 ? -127 : q);
    pack |= ((u32)(u8)(s8)q) << (8*e);
  }
  const int dir = row >> 10, n = row & 1023;
  const int g = n >> 8, j = n & 255, w2 = j >> 4, lr2 = j & 15;
  const int kk = lane >> 4, lq2 = (lane >> 2) & 3, e4 = lane & 3;
  u32* wq32 = (u32*)wq;
  wq32[dir*65536 + (((g*16 + w2)*4 + kk)*64 + lq2*16 + lr2)*4 + e4] = pack;
  if (lane == 0) sc2[row] = m * (1.f/16129.f);
}

// ---------------- K1: features, 1024 blocks x 8 sb-tiles (weights staged once) ----------------
__global__ __launch_bounds__(256) void k1_feat(
    const int* __restrict__ X, const int* __restrict__ tg, const int* __restrict__ ch,
    const float* __restrict__ etab, const float* __restrict__ ttab, const float* __restrict__ ctab,
    const float* __restrict__ cw, const float* __restrict__ cb, u16* __restrict__ feat)
{
  const int b = blockIdx.y, tid = threadIdx.x;
  __shared__ float ce_s[66*60];
  __shared__ float w_s[150*52];
  // stage conv weights ONCE: w_s[(cc*3+dc)*52 + ce]
  for (int i = tid; i < 7500; i += 256){
    int cc = i/150, r2 = i - cc*150;
    int ce = r2/3, dc = r2 - ce*3;
    w_s[(cc*3 + dc)*52 + ce] = cw[i];
  }
  const int li = tid & 15, jg = tid >> 4;

  for (int it = 0; it < 8; it++){
    const int sb = blockIdx.x*8 + it;
    __syncthreads();   // w_s ready (it=0) / prev iter's compute done (it>0)
    // embed rows: 4 rows x 150 word-pairs
    for (int i = tid; i < 600; i += 256){
      int wl = i/150, j = i - wl*150;
      int s = sb*4 + wl;
      int idx = X[b*512 + s];
      float2 f = *(const float2*)(etab + (size_t)idx*300 + j*2);
      *(u32*)(feat + (size_t)(s*64 + b)*416 + j*2) = (u32)f2bf(f.x) | ((u32)f2bf(f.y) << 16);
    }
    // tag rows
    for (int i = tid; i < 100; i += 256){
      int wl = i/25, j = i - wl*25;
      int s = sb*4 + wl;
      int idx = tg[b*512 + s];
      float2 f = *(const float2*)(ttab + (size_t)idx*50 + j*2);
      *(u32*)(feat + (size_t)(s*64 + b)*416 + 300 + j*2) = (u32)f2bf(f.x) | ((u32)f2bf(f.y) << 16);
    }
    // zero pad cols 400..415
    if (tid < 32){
      int wl = tid>>3, j = tid&7;
      int s = sb*4 + wl;
      *(u32*)(feat + (size_t)(s*64 + b)*416 + 400 + j*2) = 0u;
    }
    // char embeddings, 66 halo rows x 50
    for (int i = tid; i < 3300; i += 256){
      int qq = i/50, ce = i - qq*50;
      int p = sb*64 - 1 + qq;
      float v = 0.f;
      if (p >= 0 && p < 8192){
        int ci = ch[b*8192 + p];
        v = ctab[ci*50 + ce];
      }
      ce_s[qq*60 + ce] = v;
    }
    __syncthreads();
    // conv main: thread (li, jg -> cc = 3jg..3jg+2), pl = 16k+li
    float acc[4][3];
    #pragma unroll
    for (int k=0;k<4;k++){ acc[k][0]=0.f; acc[k][1]=0.f; acc[k][2]=0.f; }
    #pragma unroll
    for (int dc = 0; dc < 3; dc++){
      for (int ceb = 0; ceb < 48; ceb += 4){
        f32x4 w0 = *(const f32x4*)&w_s[((3*jg+0)*3 + dc)*52 + ceb];
        f32x4 w1 = *(const f32x4*)&w_s[((3*jg+1)*3 + dc)*52 + ceb];
        f32x4 w2 = *(const f32x4*)&w_s[((3*jg+2)*3 + dc)*52 + ceb];
        #pragma unroll
        for (int k = 0; k < 4; k++){
          f32x4 cv = *(const f32x4*)&ce_s[(16*k + li + dc)*60 + ceb];
          #pragma unroll
          for (int e = 0; e < 4; e++){
            acc[k][0] += cv[e]*w0[e];
            acc[k][1] += cv[e]*w1[e];
            acc[k][2] += cv[e]*w2[e];
          }
        }
      }
      float w0a = w_s[((3*jg+0)*3+dc)*52 + 48], w0b = w_s[((3*jg+0)*3+dc)*52 + 49];
      float w1a = w_s[((3*jg+1)*3+dc)*52 + 48], w1b = w_s[((3*jg+1)*3+dc)*52 + 49];
      float w2a = w_s[((3*jg+2)*3+dc)*52 + 48], w2b = w_s[((3*jg+2)*3+dc)*52 + 49];
      #pragma unroll
      for (int k = 0; k < 4; k++){
        float ca = ce_s[(16*k + li + dc)*60 + 48];
        float cb2 = ce_s[(16*k + li + dc)*60 + 49];
        acc[k][0] += ca*w0a + cb2*w0b;
        acc[k][1] += ca*w1a + cb2*w1b;
        acc[k][2] += ca*w2a + cb2*w2b;
      }
    }
    #pragma unroll
    for (int m = 1; m < 16; m <<= 1)
      #pragma unroll
      for (int k=0;k<4;k++)
        #pragma unroll
        for (int c=0;c<3;c++)
          acc[k][c] = fmaxf(acc[k][c], __shfl_xor(acc[k][c], m, 64));
    if (li == 0){
      #pragma unroll
      for (int k=0;k<4;k++)
        #pragma unroll
        for (int c=0;c<3;c++){
          int cc = 3*jg + c;
          int s = sb*4 + k;
          feat[(size_t)(s*64 + b)*416 + 350 + cc] = f2bf(acc[k][c] + cb[cc]);
        }
    }
    // tail channels cc=48,49
    if (tid < 128){
      int pl = tid & 63, cc = 48 + (tid >> 6);
      float a2 = 0.f;
      #pragma unroll
      for (int dc = 0; dc < 3; dc++){
        for (int ceb = 0; ceb < 48; ceb += 4){
          f32x4 wv = *(const f32x4*)&w_s[(cc*3 + dc)*52 + ceb];
          f32x4 cv = *(const f32x4*)&ce_s[(pl + dc)*60 + ceb];
          a2 += cv[0]*wv[0] + cv[1]*wv[1] + cv[2]*wv[2] + cv[3]*wv[3];
        }
        a2 += ce_s[(pl+dc)*60 + 48]*w_s[(cc*3+dc)*52 + 48]
            + ce_s[(pl+dc)*60 + 49]*w_s[(cc*3+dc)*52 + 49];
      }
      #pragma unroll
      for (int m = 1; m < 16; m <<= 1) a2 = fmaxf(a2, __shfl_xor(a2, m, 64));
      if ((tid & 15) == 0){
        int s = sb*4 + ((tid & 63) >> 4);
        feat[(size_t)(s*64 + b)*416 + 350 + cc] = f2bf(a2 + cb[cc]);
      }
    }
  }
}

// ---------------- K2: gi = bf16(feat @ wih^T + bias)  [32768 x 2048] coalesced ----------------
__global__ __launch_bounds__(256) void k2_gemm(
    const u16* __restrict__ featp, const u16* __restrict__ wihp,
    const float* __restrict__ bias, u16* __restrict__ gi)
{
  const int m0 = blockIdx.y*128, n0 = blockIdx.x*128;
  const int tid = threadIdx.x, wv = tid>>6, lane = tid&63;
  const int lr = lane & 15, lq = lane >> 4;
  const int wm = (wv>>1)*64, wn = (wv&1)*64;
  __shared__ u16 As[4096], Bs[4096];
  f32x4 acc[4][4];
  #pragma unroll
  for (int a=0;a<4;a++)
    #pragma unroll
    for (int c=0;c<4;c++) acc[a][c] = (f32x4){0.f,0.f,0.f,0.f};
  for (int k0 = 0; k0 < 416; k0 += 32){
    __syncthreads();
    #pragma unroll
    for (int i = 0; i < 2; i++){
      int c = i*4 + wv;
      gld_lds16(featp + (size_t)(m0 + c*16 + (lane>>2))*416 + k0 + (lane&3)*8, &As[c*512]);
      gld_lds16(wihp  + (size_t)(n0 + c*16 + (lane>>2))*416 + k0 + (lane&3)*8, &Bs[c*512]);
    }
    __syncthreads();
    short8 af[4], bfr[4];
    #pragma unroll
    for (int mt=0; mt<4; mt++) af[mt]  = *(const short8*)(As + (wm + mt*16 + lr)*32 + lq*8);
    #pragma unroll
    for (int nt=0; nt<4; nt++) bfr[nt] = *(const short8*)(Bs + (wn + nt*16 + lr)*32 + lq*8);
    #pragma unroll
    for (int mt=0; mt<4; mt++)
      #pragma unroll
      for (int nt=0; nt<4; nt++)
        acc[mt][nt] = __builtin_amdgcn_mfma_f32_16x16x32_bf16(af[mt], bfr[nt], acc[mt][nt], 0,0,0);
  }
  #pragma unroll
  for (int nt=0; nt<4; nt++){
    float bv = bias[n0 + wn + nt*16 + lr];
    #pragma unroll
    for (int mt=0; mt<4; mt++)
      #pragma unroll
      for (int r=0; r<4; r++)
        gi[(size_t)(m0 + wm + mt*16 + lq*4 + r)*2048 + n0 + wn + nt*16 + lr]
            = f2bf(acc[mt][nt][r] + bv);
  }
}

// ---------------- K3: recurrent BiLSTM, 64 blocks x 512 thr, all-VGPR weights ----------------
// (round-8 structure: cross-wave xbuf spread cells, two lgkm barriers, 2-step prefetch)
__global__ __launch_bounds__(512, 2) void k3_lstm(
    const s8* __restrict__ wq, const float* __restrict__ sc2,
    const u16* __restrict__ gi, u16* __restrict__ hcat)
{
  const int dir = blockIdx.x >> 5;
  const int bb  = (blockIdx.x & 31) * 2;
  const int tid = threadIdx.x;
  const int w = tid >> 6, lane = tid & 63;
  const int lr = lane & 15, lq = lane >> 4;
  const int cb = tid >> 8, cj = tid & 255;

  __shared__ s8 Hs[2][4096];
  __shared__ float xbuf[2048];

  const s8* wqd = wq + dir*262144;
  int4v bq[2][4][4];
  #pragma unroll
  for (int sl = 0; sl < 2; sl++)
    #pragma unroll
    for (int g = 0; g < 4; g++)
      #pragma unroll
      for (int kk = 0; kk < 4; kk++)
        bq[sl][g][kk] = *(const int4v*)(wqd + (((((g*16 + 2*w + sl)*4 + kk)*64) + lane) << 4));

  float scl[4];
  #pragma unroll
  for (int g = 0; g < 4; g++) scl[g] = sc2[dir*1024 + g*256 + cj];

  *(uint2*)&Hs[0][tid*8] = (uint2){0u,0u};
  *(uint2*)&Hs[1][tid*8] = (uint2){0u,0u};

  float cst = 0.f;
  const ptrdiff_t dstep = dir ? -(ptrdiff_t)131072 : (ptrdiff_t)131072;
  const u16* g0 = gi + (size_t)((dir ? 511 : 0)*64 + bb + cb)*2048 + dir*1024 + cj;
  u32 gcur[4], gn1[4], gn2[4];
  #pragma unroll
  for (int g = 0; g < 4; g++) gcur[g] = g0[g*256];
  const u16* g1 = g0 + dstep;
  #pragma unroll
  for (int g = 0; g < 4; g++) gn1[g] = g1[g*256];
  const u16* gpref = g1;
  __syncthreads();

  #pragma unroll 1
  for (int t = 0; t < 512; t++){
    const int s = dir ? (511 - t) : t;
    if (t + 2 < 512) gpref += dstep;
    #pragma unroll
    for (int g = 0; g < 4; g++) gn2[g] = gpref[g*256];
    const s8* hb = Hs[t & 1];
    int4v aq[4];
    #pragma unroll
    for (int kk = 0; kk < 4; kk++)
      aq[kk] = *(const int4v*)(hb + lr*256 + ((kk*64 + lq*16) ^ (lr << 4)));
    int4v acc[2][4];
    #pragma unroll
    for (int sl = 0; sl < 2; sl++)
      #pragma unroll
      for (int g = 0; g < 4; g++) acc[sl][g] = (int4v){0,0,0,0};
    #pragma unroll
    for (int kk = 0; kk < 4; kk++)
      #pragma unroll
      for (int sl = 0; sl < 2; sl++)
        #pragma unroll
        for (int g = 0; g < 4; g++)
          acc[sl][g] = __builtin_amdgcn_mfma_i32_16x16x64_i8(aq[kk], bq[sl][g][kk], acc[sl][g], 0,0,0);
    if (lq == 0){
      #pragma unroll
      for (int sl = 0; sl < 2; sl++){
        const int j = (2*w + sl)*16 + lr;
        #pragma unroll
        for (int r = 0; r < 2; r++){
          f32x4 v = (f32x4){(float)acc[sl][0][r], (float)acc[sl][1][r],
                            (float)acc[sl][2][r], (float)acc[sl][3][r]};
          *(f32x4*)&xbuf[(r*256 + j)*4] = v;
        }
      }
    }
    bar_l();
    f32x4 p = *(const f32x4*)&xbuf[tid*4];
    float g4[4];
    #pragma unroll
    for (int g = 0; g < 4; g++) g4[g] = bf2f((u16)gcur[g]) + p[g]*scl[g];
    float iv = sigf(g4[0]), fv = sigf(g4[1]);
    float gg = tanh_f(g4[2]), ov = sigf(g4[3]);
    float c = fv*cst + iv*gg;
    cst = c;
    float h = ov * tanh_f(c);
    hcat[(size_t)(s*64 + bb + cb)*512 + dir*256 + cj] = f2bf(h);
    Hs[(t + 1) & 1][cb*256 + (cj ^ (cb << 4))] = (s8)(int)rintf(h * 127.f);
    #pragma unroll
    for (int g = 0; g < 4; g++){ gcur[g] = gn1[g]; gn1[g] = gn2[g]; }
    bar_l();
  }
}

// ---------------- K4: P = Hcat @ fc_w^T + fc_b + lm*wfc  [32768 x 16] fp32 ----------------
__global__ __launch_bounds__(256) void k4_fc(
    const u16* __restrict__ hcat, const float* __restrict__ fcw, const float* __restrict__ fcb,
    const float* __restrict__ lmp, const float* __restrict__ wfc, float* __restrict__ Pout)
{
  const int wv = threadIdx.x >> 6, lane = threadIdx.x & 63;
  const int lr = lane & 15, lq = lane >> 4;
  const int mt = blockIdx.x*4 + wv;
  short8 bfr[16];
  #pragma unroll
  for (int kk = 0; kk < 16; kk++){
    const float* wr = fcw + (size_t)lr*512 + kk*32 + lq*8;
    f32x4 w0 = *(const f32x4*)wr;
    f32x4 w1 = *(const f32x4*)(wr + 4);
    short8 sv;
    #pragma unroll
    for (int e = 0; e < 4; e++){ sv[e] = (short)f2bf(w0[e]); sv[4+e] = (short)f2bf(w1[e]); }
    bfr[kk] = sv;
  }
  f32x4 acc = (f32x4){0.f,0.f,0.f,0.f};
  #pragma unroll
  for (int kk = 0; kk < 16; kk++){
    short8 af = *(const short8*)(hcat + (size_t)(mt*16 + lr)*512 + kk*32 + lq*8);
    acc = __builtin_amdgcn_mfma_f32_16x16x32_bf16(af, bfr[kk], acc, 0,0,0);
  }
  const int cur = lr;
  float fb = fcb[cur];
  float wf = wfc[cur];
  #pragma unroll
  for (int r = 0; r < 4; r++){
    int m = mt*16 + lq*4 + r;
    int b = m & 63, s = m >> 6;
    float lmv = lmp[b*512 + s];
    Pout[(size_t)m*16 + cur] = acc[r] + fb + lmv*wf;
  }
}

// ---------------- K5: Viterbi — de-scratched (static regs, 4x unroll) ----------------
__global__ __launch_bounds__(64) void k5_vit(
    const float* __restrict__ Pg, const float* __restrict__ Am,
    float* __restrict__ dout, float* __restrict__ dl, u8* __restrict__ psi)
{
  const int b = blockIdx.x, lane = threadIdx.x;
  const int cur = lane >> 2, q = lane & 3;
  float Ar[4];
  #pragma unroll
  for (int r = 0; r < 4; r++) Ar[r] = Am[(4*q + r)*16 + cur];
  float val = Pg[(size_t)b*16 + cur];
  if (q == 0) dl[(size_t)b*16 + cur] = val;

#define FSTEP(X, S) { \
    float best = -3.0e38f; int bi = 0; \
    _Pragma("unroll") \
    for (int r = 0; r < 4; r++){ \
      float dp = __shfl(val, (4*q + r)*4, 64); \
      float sc = (dp + Ar[r]) + (X); \
      if (sc > best){ best = sc; bi = 4*q + r; } \
    } \
    { float ov = __shfl_xor(best, 1, 64); int oi = __shfl_xor(bi, 1, 64); \
      if (ov > best || (ov == best && oi < bi)){ best = ov; bi = oi; } } \
    { float ov = __shfl_xor(best, 2, 64); int oi = __shfl_xor(bi, 2, 64); \
      if (ov > best || (ov == best && oi < bi)){ best = ov; bi = oi; } } \
    val = best; \
    if (q == 0){ \
      dl[(size_t)((S)*64 + b)*16 + cur] = best; \
      psi[(size_t)((S)*64 + b)*16 + cur] = (u8)bi; \
    } }

  float x0 = Pg[(size_t)(1*64 + b)*16 + cur];
  float x1 = Pg[(size_t)(2*64 + b)*16 + cur];
  float x2 = Pg[(size_t)(3*64 + b)*16 + cur];
  float x3 = Pg[(size_t)(4*64 + b)*16 + cur];
  for (int s = 1; s < 512; s += 4){
    FSTEP(x0, s);
    if (s + 4 < 512) x0 = Pg[(size_t)((s+4)*64 + b)*16 + cur];
    if (s + 1 < 512) FSTEP(x1, s+1);
    if (s + 5 < 512) x1 = Pg[(size_t)((s+5)*64 + b)*16 + cur];
    if (s + 2 < 512) FSTEP(x2, s+2);
    if (s + 6 < 512) x2 = Pg[(size_t)((s+6)*64 + b)*16 + cur];
    if (s + 3 < 512) FSTEP(x3, s+3);
    if (s + 7 < 512) x3 = Pg[(size_t)((s+7)*64 + b)*16 + cur];
  }
#undef FSTEP

  float bv = val; int bix = cur;
  #pragma unroll
  for (int m = 1; m < 64; m <<= 1){
    float ov = __shfl_xor(bv, m, 64);
    int   oi = __shfl_xor(bix, m, 64);
    if (ov > bv || (ov == bv && oi < bix)){ bv = ov; bix = oi; }
  }
  int tag = bix;
  float score = bv;
  if (lane == 0) dout[b*512 + 511] = (float)tag;

#define BSTEP(PV, DV, T) { \
    int prev = __shfl((PV), tag, 64); \
    score += __shfl((DV), prev, 64); \
    if (lane == 0) dout[b*512 + (T)] = (float)prev; \
    tag = prev; }

  int   p0 = 0, p1 = 0, p2 = 0, p3 = 0;
  float d0 = 0.f, d1 = 0.f, d2 = 0.f, d3 = 0.f;
  if (lane < 16){
    p0 = psi[(size_t)(511*64 + b)*16 + lane]; d0 = dl[(size_t)(510*64 + b)*16 + lane];
    p1 = psi[(size_t)(510*64 + b)*16 + lane]; d1 = dl[(size_t)(509*64 + b)*16 + lane];
    p2 = psi[(size_t)(509*64 + b)*16 + lane]; d2 = dl[(size_t)(508*64 + b)*16 + lane];
    p3 = psi[(size_t)(508*64 + b)*16 + lane]; d3 = dl[(size_t)(507*64 + b)*16 + lane];
  }
  for (int t = 510; t >= 0; t -= 4){
    BSTEP(p0, d0, t);
    if (t - 4 >= 0 && lane < 16){
      p0 = psi[(size_t)((t-3)*64 + b)*16 + lane]; d0 = dl[(size_t)((t-4)*64 + b)*16 + lane];
    }
    if (t - 1 >= 0) BSTEP(p1, d1, t-1);
    if (t - 5 >= 0 && lane < 16){
      p1 = psi[(size_t)((t-4)*64 + b)*16 + lane]; d1 = dl[(size_t)((t-5)*64 + b)*16 + lane];
    }
    if (t - 2 >= 0) BSTEP(p2, d2, t-2);
    if (t - 6 >= 0 && lane < 16){
      p2 = psi[(size_t)((t-5)*64 + b)*16 + lane]; d2 = dl[(size_t)((t-6)*64 + b)*16 + lane];
    }
    if (t - 3 >= 0) BSTEP(p3, d3, t-3);
    if (t - 7 >= 0 && lane < 16){
      p3 = psi[(size_t)((t-6)*64 + b)*16 + lane]; d3 = dl[(size_t)((t-7)*64 + b)*16 + lane];
    }
  }
#undef BSTEP
  if (lane == 0) dout[32768 + b] = score;
}

// ---------------- launcher ----------------
extern "C" void kernel_launch(void* const* d_in, const int* in_sizes, int n_in,
                              void* d_out, int out_size, void* d_ws, size_t ws_size,
                              hipStream_t stream)
{
  (void)in_sizes; (void)n_in; (void)out_size;
  if (ws_size < REQUIRED) return;

  const int*   X    = (const int*)d_in[0];
  const float* lm   = (const float*)d_in[1];
  const int*   tg   = (const int*)d_in[2];
  const int*   ch   = (const int*)d_in[3];
  const float* etab = (const float*)d_in[4];
  const float* ttab = (const float*)d_in[5];
  const float* ctab = (const float*)d_in[6];
  const float* cw   = (const float*)d_in[7];
  const float* cb   = (const float*)d_in[8];
  const float* wihf = (const float*)d_in[9];
  const float* whhf = (const float*)d_in[10];
  const float* bihf = (const float*)d_in[11];
  const float* bhhf = (const float*)d_in[12];
  const float* wihb = (const float*)d_in[13];
  const float* whhb = (const float*)d_in[14];
  const float* bihb = (const float*)d_in[15];
  const float* bhhb = (const float*)d_in[16];
  const float* fcw  = (const float*)d_in[17];
  const float* fcb  = (const float*)d_in[18];
  const float* Am   = (const float*)d_in[19];
  const float* wdp  = (const float*)d_in[20];

  char* ws = (char*)d_ws;
  u16*   gi   = (u16*)(ws + OFF_GI);
  u16*   feat = (u16*)(ws + OFF_B);
  u16*   hcat = (u16*)(ws + OFF_B);
  u16*   wih  = (u16*)(ws + OFF_WIH);
  s8*    wq   = (s8*)(ws + OFF_WQ);
  float* sc2  = (float*)(ws + OFF_SC);
  float* Pg   = (float*)(ws + OFF_P);
  float* dlt  = (float*)(ws + OFF_DL);
  u8*    psi  = (u8*)(ws + OFF_PSI);
  float* bias = (float*)(ws + OFF_BIAS);
  float* wfc  = (float*)(ws + OFF_WFC);
  float* dout = (float*)d_out;

  k0_pack<<<2048, 256, 0, stream>>>(wihf, wihb, wih);
  k0qm<<<513, 256, 0, stream>>>(whhf, whhb, wq, sc2,
                                bihf, bhhf, bihb, bhhb, fcw, wdp, bias, wfc);
  k1_feat<<<dim3(16, 64), 256, 0, stream>>>(X, tg, ch, etab, ttab, ctab, cw, cb, feat);
  k2_gemm<<<dim3(16, 256), 256, 0, stream>>>(feat, wih, bias, gi);
  k3_lstm<<<64, 512, 0, stream>>>(wq, sc2, gi, hcat);
  k4_fc<<<512, 256, 0, stream>>>(hcat, fcw, fcb, lm, wfc, Pg);
  k5_vit<<<64, 64, 0, stream>>>(Pg, Am, dout, dlt, psi);
}

// Round 12
// 1076.434 us; speedup vs baseline: 1.2929x; 1.1096x over previous
//
#include <hip/hip_runtime.h>

// BiLSTM-CRF on MI355X. Round 12: K5 Viterbi shuffle-free (replicated delta +
// readlane broadcast; readlane backtrace); k0_pack merged into k0_all;
// K3 + setprio around MFMA. K1/K2/K3/K4 otherwise identical to round 11.

#define DEV __device__ __forceinline__
typedef unsigned short u16;
typedef unsigned int   u32;
typedef unsigned char  u8;
typedef signed char    s8;
using short8  = __attribute__((ext_vector_type(8))) short;
using f32x4   = __attribute__((ext_vector_type(4))) float;
using int4v   = __attribute__((ext_vector_type(4))) int;

DEV float bf2f(u16 u){ union{u32 i; float f;} v; v.i = ((u32)u)<<16; return v.f; }
DEV u16 f2bf(float f){ u32 x = __float_as_uint(f); return (u16)((x + 0x7fffu + ((x>>16)&1u)) >> 16); }
DEV float sigf(float x){ return __builtin_amdgcn_rcpf(1.f + __expf(-x)); }
DEV float tanh_f(float x){ return 1.f - 2.f*__builtin_amdgcn_rcpf(__expf(2.f*x) + 1.f); }
DEV float rdlane_f(float v, int l){
  return __uint_as_float(__builtin_amdgcn_readlane(__float_as_uint(v), l));
}

typedef __attribute__((address_space(1))) const u32 GU;
typedef __attribute__((address_space(3))) u32 LU;
DEV void gld_lds16(const void* g, void* l){
  __builtin_amdgcn_global_load_lds((GU*)g, (LU*)l, 16, 0, 0);
}
DEV void bar_l(){
  __builtin_amdgcn_sched_barrier(0);
  asm volatile("s_waitcnt lgkmcnt(0)" ::: "memory");
  __builtin_amdgcn_s_barrier();
  __builtin_amdgcn_sched_barrier(0);
}

// ---------------- ws layout (aliased; total ~170MB) ----------------
static const size_t OFF_GI   = 0;
static const size_t OFF_P    = 0;
static const size_t OFF_DL   = OFF_P  + (size_t)32768*16*4;
static const size_t OFF_PSI  = OFF_DL + (size_t)32768*16*4;
static const size_t OFF_B    = (size_t)134217728;
static const size_t OFF_WIH  = OFF_B    + (size_t)33554432;
static const size_t OFF_WQ   = OFF_WIH  + (size_t)1703936;   // 512KB i8 frags
static const size_t OFF_SC   = OFF_WQ   + (size_t)524288;    // 8KB scales
static const size_t OFF_BIAS = OFF_SC   + 8192;
static const size_t OFF_WFC  = OFF_BIAS + 8192;
static const size_t REQUIRED = OFF_WFC  + 256;

// ---------------- K0all: quantize W_hh (0..511) | bias/wfc (512) | pack W_ih (513..2560) ----------------
__global__ __launch_bounds__(256) void k0_all(
    const float* __restrict__ whhf, const float* __restrict__ whhb,
    s8* __restrict__ wq, float* __restrict__ sc2,
    const float* bihf, const float* bhhf, const float* bihb, const float* bhhb,
    const float* fcw, const float* wdp, float* bias, float* wfc,
    const float* __restrict__ wihf, const float* __restrict__ wihb, u16* __restrict__ wih)
{
  __shared__ float red[256];
  const int tid = threadIdx.x;
  const int bx = blockIdx.x;
  if (bx > 512){
    const int n = bx - 513;
    const float* src = (n < 1024) ? (wihf + (size_t)n*400) : (wihb + (size_t)(n-1024)*400);
    u32* dst = (u32*)(wih + (size_t)n*416);
    if (tid < 208){
      int j = tid*2;
      u32 v = 0u;
      if (j < 400){
        float2 f = *(const float2*)(src + j);
        v = (u32)f2bf(f.x) | ((u32)f2bf(f.y) << 16);
      }
      dst[tid] = v;
    }
    return;
  }
  if (bx == 512){
    for (int n = tid; n < 2048; n += 256){
      bias[n] = (n < 1024) ? (bihf[n] + bhhf[n]) : (bihb[n-1024] + bhhb[n-1024]);
    }
    const int cur = tid & 15, part = tid >> 4;
    float s = 0.f;
    for (int k = part*32; k < part*32 + 32; k++) s += fcw[cur*512 + k] * wdp[k];
    red[tid] = s;
    __syncthreads();
    if (tid < 16){
      float t = 0.f;
      #pragma unroll
      for (int p = 0; p < 16; p++) t += red[p*16 + tid];
      wfc[tid] = t;
    }
    return;
  }
  const int row = bx*4 + (tid >> 6);
  const int lane = tid & 63;
  const float* src = (row < 1024) ? (whhf + (size_t)row*256)
                                  : (whhb + (size_t)(row-1024)*256);
  f32x4 v = *(const f32x4*)(src + lane*4);
  float m = fmaxf(fmaxf(fabsf(v[0]), fabsf(v[1])), fmaxf(fabsf(v[2]), fabsf(v[3])));
  #pragma unroll
  for (int d = 1; d < 64; d <<= 1) m = fmaxf(m, __shfl_xor(m, d, 64));
  float inv = 127.f / (m + 1e-30f);
  u32 pack = 0;
  #pragma unroll
  for (int e = 0; e < 4; e++){
    int q = (int)rintf(v[e]*inv);
    q = q > 127 ? 127 : (q < -127 ? -127 : q);
    pack |= ((u32)(u8)(s8)q) << (8*e);
  }
  const int dir = row >> 10, n = row & 1023;
  const int g = n >> 8, j = n & 255, w2 = j >> 4, lr2 = j & 15;
  const int kk = lane >> 4, lq2 = (lane >> 2) & 3, e4 = lane & 3;
  u32* wq32 = (u32*)wq;
  wq32[dir*65536 + (((g*16 + w2)*4 + kk)*64 + lq2*16 + lr2)*4 + e4] = pack;
  if (lane == 0) sc2[row] = m * (1.f/16129.f);
}

// ---------------- K1: features, 1024 blocks x 8 sb-tiles ----------------
__global__ __launch_bounds__(256) void k1_feat(
    const int* __restrict__ X, const int* __restrict__ tg, const int* __restrict__ ch,
    const float* __restrict__ etab, const float* __restrict__ ttab, const float* __restrict__ ctab,
    const float* __restrict__ cw, const float* __restrict__ cb, u16* __restrict__ feat)
{
  const int b = blockIdx.y, tid = threadIdx.x;
  __shared__ float ce_s[66*60];
  __shared__ float w_s[150*52];
  for (int i = tid; i < 7500; i += 256){
    int cc = i/150, r2 = i - cc*150;
    int ce = r2/3, dc = r2 - ce*3;
    w_s[(cc*3 + dc)*52 + ce] = cw[i];
  }
  const int li = tid & 15, jg = tid >> 4;

  for (int it = 0; it < 8; it++){
    const int sb = blockIdx.x*8 + it;
    __syncthreads();
    for (int i = tid; i < 600; i += 256){
      int wl = i/150, j = i - wl*150;
      int s = sb*4 + wl;
      int idx = X[b*512 + s];
      float2 f = *(const float2*)(etab + (size_t)idx*300 + j*2);
      *(u32*)(feat + (size_t)(s*64 + b)*416 + j*2) = (u32)f2bf(f.x) | ((u32)f2bf(f.y) << 16);
    }
    for (int i = tid; i < 100; i += 256){
      int wl = i/25, j = i - wl*25;
      int s = sb*4 + wl;
      int idx = tg[b*512 + s];
      float2 f = *(const float2*)(ttab + (size_t)idx*50 + j*2);
      *(u32*)(feat + (size_t)(s*64 + b)*416 + 300 + j*2) = (u32)f2bf(f.x) | ((u32)f2bf(f.y) << 16);
    }
    if (tid < 32){
      int wl = tid>>3, j = tid&7;
      int s = sb*4 + wl;
      *(u32*)(feat + (size_t)(s*64 + b)*416 + 400 + j*2) = 0u;
    }
    for (int i = tid; i < 3300; i += 256){
      int qq = i/50, ce = i - qq*50;
      int p = sb*64 - 1 + qq;
      float v = 0.f;
      if (p >= 0 && p < 8192){
        int ci = ch[b*8192 + p];
        v = ctab[ci*50 + ce];
      }
      ce_s[qq*60 + ce] = v;
    }
    __syncthreads();
    float acc[4][3];
    #pragma unroll
    for (int k=0;k<4;k++){ acc[k][0]=0.f; acc[k][1]=0.f; acc[k][2]=0.f; }
    #pragma unroll
    for (int dc = 0; dc < 3; dc++){
      for (int ceb = 0; ceb < 48; ceb += 4){
        f32x4 w0 = *(const f32x4*)&w_s[((3*jg+0)*3 + dc)*52 + ceb];
        f32x4 w1 = *(const f32x4*)&w_s[((3*jg+1)*3 + dc)*52 + ceb];
        f32x4 w2 = *(const f32x4*)&w_s[((3*jg+2)*3 + dc)*52 + ceb];
        #pragma unroll
        for (int k = 0; k < 4; k++){
          f32x4 cv = *(const f32x4*)&ce_s[(16*k + li + dc)*60 + ceb];
          #pragma unroll
          for (int e = 0; e < 4; e++){
            acc[k][0] += cv[e]*w0[e];
            acc[k][1] += cv[e]*w1[e];
            acc[k][2] += cv[e]*w2[e];
          }
        }
      }
      float w0a = w_s[((3*jg+0)*3+dc)*52 + 48], w0b = w_s[((3*jg+0)*3+dc)*52 + 49];
      float w1a = w_s[((3*jg+1)*3+dc)*52 + 48], w1b = w_s[((3*jg+1)*3+dc)*52 + 49];
      float w2a = w_s[((3*jg+2)*3+dc)*52 + 48], w2b = w_s[((3*jg+2)*3+dc)*52 + 49];
      #pragma unroll
      for (int k = 0; k < 4; k++){
        float ca = ce_s[(16*k + li + dc)*60 + 48];
        float cb2 = ce_s[(16*k + li + dc)*60 + 49];
        acc[k][0] += ca*w0a + cb2*w0b;
        acc[k][1] += ca*w1a + cb2*w1b;
        acc[k][2] += ca*w2a + cb2*w2b;
      }
    }
    #pragma unroll
    for (int m = 1; m < 16; m <<= 1)
      #pragma unroll
      for (int k=0;k<4;k++)
        #pragma unroll
        for (int c=0;c<3;c++)
          acc[k][c] = fmaxf(acc[k][c], __shfl_xor(acc[k][c], m, 64));
    if (li == 0){
      #pragma unroll
      for (int k=0;k<4;k++)
        #pragma unroll
        for (int c=0;c<3;c++){
          int cc = 3*jg + c;
          int s = sb*4 + k;
          feat[(size_t)(s*64 + b)*416 + 350 + cc] = f2bf(acc[k][c] + cb[cc]);
        }
    }
    if (tid < 128){
      int pl = tid & 63, cc = 48 + (tid >> 6);
      float a2 = 0.f;
      #pragma unroll
      for (int dc = 0; dc < 3; dc++){
        for (int ceb = 0; ceb < 48; ceb += 4){
          f32x4 wv = *(const f32x4*)&w_s[(cc*3 + dc)*52 + ceb];
          f32x4 cv = *(const f32x4*)&ce_s[(pl + dc)*60 + ceb];
          a2 += cv[0]*wv[0] + cv[1]*wv[1] + cv[2]*wv[2] + cv[3]*wv[3];
        }
        a2 += ce_s[(pl+dc)*60 + 48]*w_s[(cc*3+dc)*52 + 48]
            + ce_s[(pl+dc)*60 + 49]*w_s[(cc*3+dc)*52 + 49];
      }
      #pragma unroll
      for (int m = 1; m < 16; m <<= 1) a2 = fmaxf(a2, __shfl_xor(a2, m, 64));
      if ((tid & 15) == 0){
        int s = sb*4 + ((tid & 63) >> 4);
        feat[(size_t)(s*64 + b)*416 + 350 + cc] = f2bf(a2 + cb[cc]);
      }
    }
  }
}

// ---------------- K2: gi = bf16(feat @ wih^T + bias)  [32768 x 2048] coalesced ----------------
__global__ __launch_bounds__(256) void k2_gemm(
    const u16* __restrict__ featp, const u16* __restrict__ wihp,
    const float* __restrict__ bias, u16* __restrict__ gi)
{
  const int m0 = blockIdx.y*128, n0 = blockIdx.x*128;
  const int tid = threadIdx.x, wv = tid>>6, lane = tid&63;
  const int lr = lane & 15, lq = lane >> 4;
  const int wm = (wv>>1)*64, wn = (wv&1)*64;
  __shared__ u16 As[4096], Bs[4096];
  f32x4 acc[4][4];
  #pragma unroll
  for (int a=0;a<4;a++)
    #pragma unroll
    for (int c=0;c<4;c++) acc[a][c] = (f32x4){0.f,0.f,0.f,0.f};
  for (int k0 = 0; k0 < 416; k0 += 32){
    __syncthreads();
    #pragma unroll
    for (int i = 0; i < 2; i++){
      int c = i*4 + wv;
      gld_lds16(featp + (size_t)(m0 + c*16 + (lane>>2))*416 + k0 + (lane&3)*8, &As[c*512]);
      gld_lds16(wihp  + (size_t)(n0 + c*16 + (lane>>2))*416 + k0 + (lane&3)*8, &Bs[c*512]);
    }
    __syncthreads();
    short8 af[4], bfr[4];
    #pragma unroll
    for (int mt=0; mt<4; mt++) af[mt]  = *(const short8*)(As + (wm + mt*16 + lr)*32 + lq*8);
    #pragma unroll
    for (int nt=0; nt<4; nt++) bfr[nt] = *(const short8*)(Bs + (wn + nt*16 + lr)*32 + lq*8);
    #pragma unroll
    for (int mt=0; mt<4; mt++)
      #pragma unroll
      for (int nt=0; nt<4; nt++)
        acc[mt][nt] = __builtin_amdgcn_mfma_f32_16x16x32_bf16(af[mt], bfr[nt], acc[mt][nt], 0,0,0);
  }
  #pragma unroll
  for (int nt=0; nt<4; nt++){
    float bv = bias[n0 + wn + nt*16 + lr];
    #pragma unroll
    for (int mt=0; mt<4; mt++)
      #pragma unroll
      for (int r=0; r<4; r++)
        gi[(size_t)(m0 + wm + mt*16 + lq*4 + r)*2048 + n0 + wn + nt*16 + lr]
            = f2bf(acc[mt][nt][r] + bv);
  }
}

// ---------------- K3: recurrent BiLSTM, 64 blocks x 512 thr, all-VGPR weights ----------------
__global__ __launch_bounds__(512, 2) void k3_lstm(
    const s8* __restrict__ wq, const float* __restrict__ sc2,
    const u16* __restrict__ gi, u16* __restrict__ hcat)
{
  const int dir = blockIdx.x >> 5;
  const int bb  = (blockIdx.x & 31) * 2;
  const int tid = threadIdx.x;
  const int w = tid >> 6, lane = tid & 63;
  const int lr = lane & 15, lq = lane >> 4;
  const int cb = tid >> 8, cj = tid & 255;

  __shared__ s8 Hs[2][4096];
  __shared__ float xbuf[2048];

  const s8* wqd = wq + dir*262144;
  int4v bq[2][4][4];
  #pragma unroll
  for (int sl = 0; sl < 2; sl++)
    #pragma unroll
    for (int g = 0; g < 4; g++)
      #pragma unroll
      for (int kk = 0; kk < 4; kk++)
        bq[sl][g][kk] = *(const int4v*)(wqd + (((((g*16 + 2*w + sl)*4 + kk)*64) + lane) << 4));

  float scl[4];
  #pragma unroll
  for (int g = 0; g < 4; g++) scl[g] = sc2[dir*1024 + g*256 + cj];

  *(uint2*)&Hs[0][tid*8] = (uint2){0u,0u};
  *(uint2*)&Hs[1][tid*8] = (uint2){0u,0u};

  float cst = 0.f;
  const ptrdiff_t dstep = dir ? -(ptrdiff_t)131072 : (ptrdiff_t)131072;
  const u16* g0 = gi + (size_t)((dir ? 511 : 0)*64 + bb + cb)*2048 + dir*1024 + cj;
  u32 gcur[4], gn1[4], gn2[4];
  #pragma unroll
  for (int g = 0; g < 4; g++) gcur[g] = g0[g*256];
  const u16* g1 = g0 + dstep;
  #pragma unroll
  for (int g = 0; g < 4; g++) gn1[g] = g1[g*256];
  const u16* gpref = g1;
  __syncthreads();

  #pragma unroll 1
  for (int t = 0; t < 512; t++){
    const int s = dir ? (511 - t) : t;
    if (t + 2 < 512) gpref += dstep;
    #pragma unroll
    for (int g = 0; g < 4; g++) gn2[g] = gpref[g*256];
    const s8* hb = Hs[t & 1];
    int4v aq[4];
    #pragma unroll
    for (int kk = 0; kk < 4; kk++)
      aq[kk] = *(const int4v*)(hb + lr*256 + ((kk*64 + lq*16) ^ (lr << 4)));
    int4v acc[2][4];
    #pragma unroll
    for (int sl = 0; sl < 2; sl++)
      #pragma unroll
      for (int g = 0; g < 4; g++) acc[sl][g] = (int4v){0,0,0,0};
    __builtin_amdgcn_s_setprio(1);
    #pragma unroll
    for (int kk = 0; kk < 4; kk++)
      #pragma unroll
      for (int sl = 0; sl < 2; sl++)
        #pragma unroll
        for (int g = 0; g < 4; g++)
          acc[sl][g] = __builtin_amdgcn_mfma_i32_16x16x64_i8(aq[kk], bq[sl][g][kk], acc[sl][g], 0,0,0);
    __builtin_amdgcn_s_setprio(0);
    if (lq == 0){
      #pragma unroll
      for (int sl = 0; sl < 2; sl++){
        const int j = (2*w + sl)*16 + lr;
        #pragma unroll
        for (int r = 0; r < 2; r++){
          f32x4 v = (f32x4){(float)acc[sl][0][r], (float)acc[sl][1][r],
                            (float)acc[sl][2][r], (float)acc[sl][3][r]};
          *(f32x4*)&xbuf[(r*256 + j)*4] = v;
        }
      }
    }
    bar_l();
    f32x4 p = *(const f32x4*)&xbuf[tid*4];
    float g4[4];
    #pragma unroll
    for (int g = 0; g < 4; g++) g4[g] = bf2f((u16)gcur[g]) + p[g]*scl[g];
    float iv = sigf(g4[0]), fv = sigf(g4[1]);
    float gg = tanh_f(g4[2]), ov = sigf(g4[3]);
    float c = fv*cst + iv*gg;
    cst = c;
    float h = ov * tanh_f(c);
    hcat[(size_t)(s*64 + bb + cb)*512 + dir*256 + cj] = f2bf(h);
    Hs[(t + 1) & 1][cb*256 + (cj ^ (cb << 4))] = (s8)(int)rintf(h * 127.f);
    #pragma unroll
    for (int g = 0; g < 4; g++){ gcur[g] = gn1[g]; gn1[g] = gn2[g]; }
    bar_l();
  }
}

// ---------------- K4: P = Hcat @ fc_w^T + fc_b + lm*wfc  [32768 x 16] fp32 ----------------
__global__ __launch_bounds__(256) void k4_fc(
    const u16* __restrict__ hcat, const float* __restrict__ fcw, const float* __restrict__ fcb,
    const float* __restrict__ lmp, const float* __restrict__ wfc, float* __restrict__ Pout)
{
  const int wv = threadIdx.x >> 6, lane = threadIdx.x & 63;
  const int lr = lane & 15, lq = lane >> 4;
  const int mt = blockIdx.x*4 + wv;
  short8 bfr[16];
  #pragma unroll
  for (int kk = 0; kk < 16; kk++){
    const float* wr = fcw + (size_t)lr*512 + kk*32 + lq*8;
    f32x4 w0 = *(const f32x4*)wr;
    f32x4 w1 = *(const f32x4*)(wr + 4);
    short8 sv;
    #pragma unroll
    for (int e = 0; e < 4; e++){ sv[e] = (short)f2bf(w0[e]); sv[4+e] = (short)f2bf(w1[e]); }
    bfr[kk] = sv;
  }
  f32x4 acc = (f32x4){0.f,0.f,0.f,0.f};
  #pragma unroll
  for (int kk = 0; kk < 16; kk++){
    short8 af = *(const short8*)(hcat + (size_t)(mt*16 + lr)*512 + kk*32 + lq*8);
    acc = __builtin_amdgcn_mfma_f32_16x16x32_bf16(af, bfr[kk], acc, 0,0,0);
  }
  const int cur = lr;
  float fb = fcb[cur];
  float wf = wfc[cur];
  #pragma unroll
  for (int r = 0; r < 4; r++){
    int m = mt*16 + lq*4 + r;
    int b = m & 63, s = m >> 6;
    float lmv = lmp[b*512 + s];
    Pout[(size_t)m*16 + cur] = acc[r] + fb + lmv*wf;
  }
}

// ---------------- K5: Viterbi — shuffle-free (replicated delta + readlane) ----------------
__global__ __launch_bounds__(64) void k5_vit(
    const float* __restrict__ Pg, const float* __restrict__ Am,
    float* __restrict__ dout, float* __restrict__ dl, u8* __restrict__ psi)
{
  const int b = blockIdx.x, lane = threadIdx.x;
  const int cur = lane & 15;
  float Ar[16];
  #pragma unroll
  for (int p = 0; p < 16; p++) Ar[p] = Am[p*16 + cur];
  float dreg[16];
  {
    float v0 = Pg[(size_t)b*16 + cur];
    if (lane < 16) dl[(size_t)b*16 + cur] = v0;
    #pragma unroll
    for (int c = 0; c < 16; c++) dreg[c] = rdlane_f(v0, c);
  }

#define FSTEP(X, S) { \
    float v_[16]; \
    _Pragma("unroll") \
    for (int p = 0; p < 16; p++) v_[p] = dreg[p] + Ar[p]; \
    float m1[8]; int i1[8]; \
    _Pragma("unroll") \
    for (int k = 0; k < 8; k++){ bool c_ = v_[2*k] >= v_[2*k+1]; \
      m1[k] = c_ ? v_[2*k] : v_[2*k+1]; i1[k] = c_ ? 2*k : 2*k+1; } \
    float m2[4]; int i2[4]; \
    _Pragma("unroll") \
    for (int k = 0; k < 4; k++){ bool c_ = m1[2*k] >= m1[2*k+1]; \
      m2[k] = c_ ? m1[2*k] : m1[2*k+1]; i2[k] = c_ ? i1[2*k] : i1[2*k+1]; } \
    float m3[2]; int i3[2]; \
    _Pragma("unroll") \
    for (int k = 0; k < 2; k++){ bool c_ = m2[2*k] >= m2[2*k+1]; \
      m3[k] = c_ ? m2[2*k] : m2[2*k+1]; i3[k] = c_ ? i2[2*k] : i2[2*k+1]; } \
    bool cf_ = m3[0] >= m3[1]; \
    float best = (cf_ ? m3[0] : m3[1]) + (X); \
    int bi = cf_ ? i3[0] : i3[1]; \
    if (lane < 16){ \
      dl[(size_t)((S)*64 + b)*16 + cur] = best; \
      psi[(size_t)((S)*64 + b)*16 + cur] = (u8)bi; \
    } \
    _Pragma("unroll") \
    for (int c = 0; c < 16; c++) dreg[c] = rdlane_f(best, c); \
  }

  // forward scan, 4x unroll, named prefetch regs
  float x0 = Pg[(size_t)(1*64 + b)*16 + cur];
  float x1 = Pg[(size_t)(2*64 + b)*16 + cur];
  float x2 = Pg[(size_t)(3*64 + b)*16 + cur];
  float x3 = Pg[(size_t)(4*64 + b)*16 + cur];
  for (int s = 1; s < 512; s += 4){
    FSTEP(x0, s);
    if (s + 4 < 512) x0 = Pg[(size_t)((s+4)*64 + b)*16 + cur];
    if (s + 1 < 512) FSTEP(x1, s+1);
    if (s + 5 < 512) x1 = Pg[(size_t)((s+5)*64 + b)*16 + cur];
    if (s + 2 < 512) FSTEP(x2, s+2);
    if (s + 6 < 512) x2 = Pg[(size_t)((s+6)*64 + b)*16 + cur];
    if (s + 3 < 512) FSTEP(x3, s+3);
    if (s + 7 < 512) x3 = Pg[(size_t)((s+7)*64 + b)*16 + cur];
  }
#undef FSTEP

  // final argmax (uniform; first-index tie-break)
  float bv = dreg[0]; int bix = 0;
  #pragma unroll
  for (int c = 1; c < 16; c++){ if (dreg[c] > bv){ bv = dreg[c]; bix = c; } }
  int tag = bix;
  float score = bv;
  if (lane == 0) dout[b*512 + 511] = (float)tag;

#define BSTEP(PV, DV, T) { \
    int prev = __builtin_amdgcn_readlane((PV), tag); \
    score += rdlane_f((DV), prev); \
    if (lane == 0) dout[b*512 + (T)] = (float)prev; \
    tag = prev; }

  int   p0 = 0, p1 = 0, p2 = 0, p3 = 0;
  float d0 = 0.f, d1 = 0.f, d2 = 0.f, d3 = 0.f;
  if (lane < 16){
    p0 = psi[(size_t)(511*64 + b)*16 + lane]; d0 = dl[(size_t)(510*64 + b)*16 + lane];
    p1 = psi[(size_t)(510*64 + b)*16 + lane]; d1 = dl[(size_t)(509*64 + b)*16 + lane];
    p2 = psi[(size_t)(509*64 + b)*16 + lane]; d2 = dl[(size_t)(508*64 + b)*16 + lane];
    p3 = psi[(size_t)(508*64 + b)*16 + lane]; d3 = dl[(size_t)(507*64 + b)*16 + lane];
  }
  for (int t = 510; t >= 0; t -= 4){
    BSTEP(p0, d0, t);
    if (t - 4 >= 0 && lane < 16){
      p0 = psi[(size_t)((t-3)*64 + b)*16 + lane]; d0 = dl[(size_t)((t-4)*64 + b)*16 + lane];
    }
    if (t - 1 >= 0) BSTEP(p1, d1, t-1);
    if (t - 5 >= 0 && lane < 16){
      p1 = psi[(size_t)((t-4)*64 + b)*16 + lane]; d1 = dl[(size_t)((t-5)*64 + b)*16 + lane];
    }
    if (t - 2 >= 0) BSTEP(p2, d2, t-2);
    if (t - 6 >= 0 && lane < 16){
      p2 = psi[(size_t)((t-5)*64 + b)*16 + lane]; d2 = dl[(size_t)((t-6)*64 + b)*16 + lane];
    }
    if (t - 3 >= 0) BSTEP(p3, d3, t-3);
    if (t - 7 >= 0 && lane < 16){
      p3 = psi[(size_t)((t-6)*64 + b)*16 + lane]; d3 = dl[(size_t)((t-7)*64 + b)*16 + lane];
    }
  }
#undef BSTEP
  if (lane == 0) dout[32768 + b] = score;
}

// ---------------- launcher ----------------
extern "C" void kernel_launch(void* const* d_in, const int* in_sizes, int n_in,
                              void* d_out, int out_size, void* d_ws, size_t ws_size,
                              hipStream_t stream)
{
  (void)in_sizes; (void)n_in; (void)out_size;
  if (ws_size < REQUIRED) return;

  const int*   X    = (const int*)d_in[0];
  const float* lm   = (const float*)d_in[1];
  const int*   tg   = (const int*)d_in[2];
  const int*   ch   = (const int*)d_in[3];
  const float* etab = (const float*)d_in[4];
  const float* ttab = (const float*)d_in[5];
  const float* ctab = (const float*)d_in[6];
  const float* cw   = (const float*)d_in[7];
  const float* cb   = (const float*)d_in[8];
  const float* wihf = (const float*)d_in[9];
  const float* whhf = (const float*)d_in[10];
  const float* bihf = (const float*)d_in[11];
  const float* bhhf = (const float*)d_in[12];
  const float* wihb = (const float*)d_in[13];
  const float* whhb = (const float*)d_in[14];
  const float* bihb = (const float*)d_in[15];
  const float* bhhb = (const float*)d_in[16];
  const float* fcw  = (const float*)d_in[17];
  const float* fcb  = (const float*)d_in[18];
  const float* Am   = (const float*)d_in[19];
  const float* wdp  = (const float*)d_in[20];

  char* ws = (char*)d_ws;
  u16*   gi   = (u16*)(ws + OFF_GI);
  u16*   feat = (u16*)(ws + OFF_B);
  u16*   hcat = (u16*)(ws + OFF_B);
  u16*   wih  = (u16*)(ws + OFF_WIH);
  s8*    wq   = (s8*)(ws + OFF_WQ);
  float* sc2  = (float*)(ws + OFF_SC);
  float* Pg   = (float*)(ws + OFF_P);
  float* dlt  = (float*)(ws + OFF_DL);
  u8*    psi  = (u8*)(ws + OFF_PSI);
  float* bias = (float*)(ws + OFF_BIAS);
  float* wfc  = (float*)(ws + OFF_WFC);
  float* dout = (float*)d_out;

  k0_all<<<2561, 256, 0, stream>>>(whhf, whhb, wq, sc2,
                                   bihf, bhhf, bihb, bhhb, fcw, wdp, bias, wfc,
                                   wihf, wihb, wih);
  k1_feat<<<dim3(16, 64), 256, 0, stream>>>(X, tg, ch, etab, ttab, ctab, cw, cb, feat);
  k2_gemm<<<dim3(16, 256), 256, 0, stream>>>(feat, wih, bias, gi);
  k3_lstm<<<64, 512, 0, stream>>>(wq, sc2, gi, hcat);
  k4_fc<<<512, 256, 0, stream>>>(hcat, fcw, fcb, lm, wfc, Pg);
  k5_vit<<<64, 64, 0, stream>>>(Pg, Am, dout, dlt, psi);
}

// Round 13
// 1074.030 us; speedup vs baseline: 1.2958x; 1.0022x over previous
//
#include <hip/hip_runtime.h>

// BiLSTM-CRF on MI355X. Round 13: K2 double-buffered (2-phase pipeline,
// 1 barrier/K-iter, staging overlapped with compute). K0/K1/K3/K4/K5
// identical to round 12 (best-known config: 1076 us).

#define DEV __device__ __forceinline__
typedef unsigned short u16;
typedef unsigned int   u32;
typedef unsigned char  u8;
typedef signed char    s8;
using short8  = __attribute__((ext_vector_type(8))) short;
using f32x4   = __attribute__((ext_vector_type(4))) float;
using int4v   = __attribute__((ext_vector_type(4))) int;

DEV float bf2f(u16 u){ union{u32 i; float f;} v; v.i = ((u32)u)<<16; return v.f; }
DEV u16 f2bf(float f){ u32 x = __float_as_uint(f); return (u16)((x + 0x7fffu + ((x>>16)&1u)) >> 16); }
DEV float sigf(float x){ return __builtin_amdgcn_rcpf(1.f + __expf(-x)); }
DEV float tanh_f(float x){ return 1.f - 2.f*__builtin_amdgcn_rcpf(__expf(2.f*x) + 1.f); }
DEV float rdlane_f(float v, int l){
  return __uint_as_float(__builtin_amdgcn_readlane(__float_as_uint(v), l));
}

typedef __attribute__((address_space(1))) const u32 GU;
typedef __attribute__((address_space(3))) u32 LU;
DEV void gld_lds16(const void* g, void* l){
  __builtin_amdgcn_global_load_lds((GU*)g, (LU*)l, 16, 0, 0);
}
DEV void bar_l(){
  __builtin_amdgcn_sched_barrier(0);
  asm volatile("s_waitcnt lgkmcnt(0)" ::: "memory");
  __builtin_amdgcn_s_barrier();
  __builtin_amdgcn_sched_barrier(0);
}

// ---------------- ws layout (aliased; total ~170MB) ----------------
static const size_t OFF_GI   = 0;
static const size_t OFF_P    = 0;
static const size_t OFF_DL   = OFF_P  + (size_t)32768*16*4;
static const size_t OFF_PSI  = OFF_DL + (size_t)32768*16*4;
static const size_t OFF_B    = (size_t)134217728;
static const size_t OFF_WIH  = OFF_B    + (size_t)33554432;
static const size_t OFF_WQ   = OFF_WIH  + (size_t)1703936;   // 512KB i8 frags
static const size_t OFF_SC   = OFF_WQ   + (size_t)524288;    // 8KB scales
static const size_t OFF_BIAS = OFF_SC   + 8192;
static const size_t OFF_WFC  = OFF_BIAS + 8192;
static const size_t REQUIRED = OFF_WFC  + 256;

// ---------------- K0all: quantize W_hh (0..511) | bias/wfc (512) | pack W_ih (513..2560) ----------------
__global__ __launch_bounds__(256) void k0_all(
    const float* __restrict__ whhf, const float* __restrict__ whhb,
    s8* __restrict__ wq, float* __restrict__ sc2,
    const float* bihf, const float* bhhf, const float* bihb, const float* bhhb,
    const float* fcw, const float* wdp, float* bias, float* wfc,
    const float* __restrict__ wihf, const float* __restrict__ wihb, u16* __restrict__ wih)
{
  __shared__ float red[256];
  const int tid = threadIdx.x;
  const int bx = blockIdx.x;
  if (bx > 512){
    const int n = bx - 513;
    const float* src = (n < 1024) ? (wihf + (size_t)n*400) : (wihb + (size_t)(n-1024)*400);
    u32* dst = (u32*)(wih + (size_t)n*416);
    if (tid < 208){
      int j = tid*2;
      u32 v = 0u;
      if (j < 400){
        float2 f = *(const float2*)(src + j);
        v = (u32)f2bf(f.x) | ((u32)f2bf(f.y) << 16);
      }
      dst[tid] = v;
    }
    return;
  }
  if (bx == 512){
    for (int n = tid; n < 2048; n += 256){
      bias[n] = (n < 1024) ? (bihf[n] + bhhf[n]) : (bihb[n-1024] + bhhb[n-1024]);
    }
    const int cur = tid & 15, part = tid >> 4;
    float s = 0.f;
    for (int k = part*32; k < part*32 + 32; k++) s += fcw[cur*512 + k] * wdp[k];
    red[tid] = s;
    __syncthreads();
    if (tid < 16){
      float t = 0.f;
      #pragma unroll
      for (int p = 0; p < 16; p++) t += red[p*16 + tid];
      wfc[tid] = t;
    }
    return;
  }
  const int row = bx*4 + (tid >> 6);
  const int lane = tid & 63;
  const float* src = (row < 1024) ? (whhf + (size_t)row*256)
                                  : (whhb + (size_t)(row-1024)*256);
  f32x4 v = *(const f32x4*)(src + lane*4);
  float m = fmaxf(fmaxf(fabsf(v[0]), fabsf(v[1])), fmaxf(fabsf(v[2]), fabsf(v[3])));
  #pragma unroll
  for (int d = 1; d < 64; d <<= 1) m = fmaxf(m, __shfl_xor(m, d, 64));
  float inv = 127.f / (m + 1e-30f);
  u32 pack = 0;
  #pragma unroll
  for (int e = 0; e < 4; e++){
    int q = (int)rintf(v[e]*inv);
    q = q > 127 ? 127 : (q < -127 ? -127 : q);
    pack |= ((u32)(u8)(s8)q) << (8*e);
  }
  const int dir = row >> 10, n = row & 1023;
  const int g = n >> 8, j = n & 255, w2 = j >> 4, lr2 = j & 15;
  const int kk = lane >> 4, lq2 = (lane >> 2) & 3, e4 = lane & 3;
  u32* wq32 = (u32*)wq;
  wq32[dir*65536 + (((g*16 + w2)*4 + kk)*64 + lq2*16 + lr2)*4 + e4] = pack;
  if (lane == 0) sc2[row] = m * (1.f/16129.f);
}

// ---------------- K1: features, 1024 blocks x 8 sb-tiles ----------------
__global__ __launch_bounds__(256) void k1_feat(
    const int* __restrict__ X, const int* __restrict__ tg, const int* __restrict__ ch,
    const float* __restrict__ etab, const float* __restrict__ ttab, const float* __restrict__ ctab,
    const float* __restrict__ cw, const float* __restrict__ cb, u16* __restrict__ feat)
{
  const int b = blockIdx.y, tid = threadIdx.x;
  __shared__ float ce_s[66*60];
  __shared__ float w_s[150*52];
  for (int i = tid; i < 7500; i += 256){
    int cc = i/150, r2 = i - cc*150;
    int ce = r2/3, dc = r2 - ce*3;
    w_s[(cc*3 + dc)*52 + ce] = cw[i];
  }
  const int li = tid & 15, jg = tid >> 4;

  for (int it = 0; it < 8; it++){
    const int sb = blockIdx.x*8 + it;
    __syncthreads();
    for (int i = tid; i < 600; i += 256){
      int wl = i/150, j = i - wl*150;
      int s = sb*4 + wl;
      int idx = X[b*512 + s];
      float2 f = *(const float2*)(etab + (size_t)idx*300 + j*2);
      *(u32*)(feat + (size_t)(s*64 + b)*416 + j*2) = (u32)f2bf(f.x) | ((u32)f2bf(f.y) << 16);
    }
    for (int i = tid; i < 100; i += 256){
      int wl = i/25, j = i - wl*25;
      int s = sb*4 + wl;
      int idx = tg[b*512 + s];
      float2 f = *(const float2*)(ttab + (size_t)idx*50 + j*2);
      *(u32*)(feat + (size_t)(s*64 + b)*416 + 300 + j*2) = (u32)f2bf(f.x) | ((u32)f2bf(f.y) << 16);
    }
    if (tid < 32){
      int wl = tid>>3, j = tid&7;
      int s = sb*4 + wl;
      *(u32*)(feat + (size_t)(s*64 + b)*416 + 400 + j*2) = 0u;
    }
    for (int i = tid; i < 3300; i += 256){
      int qq = i/50, ce = i - qq*50;
      int p = sb*64 - 1 + qq;
      float v = 0.f;
      if (p >= 0 && p < 8192){
        int ci = ch[b*8192 + p];
        v = ctab[ci*50 + ce];
      }
      ce_s[qq*60 + ce] = v;
    }
    __syncthreads();
    float acc[4][3];
    #pragma unroll
    for (int k=0;k<4;k++){ acc[k][0]=0.f; acc[k][1]=0.f; acc[k][2]=0.f; }
    #pragma unroll
    for (int dc = 0; dc < 3; dc++){
      for (int ceb = 0; ceb < 48; ceb += 4){
        f32x4 w0 = *(const f32x4*)&w_s[((3*jg+0)*3 + dc)*52 + ceb];
        f32x4 w1 = *(const f32x4*)&w_s[((3*jg+1)*3 + dc)*52 + ceb];
        f32x4 w2 = *(const f32x4*)&w_s[((3*jg+2)*3 + dc)*52 + ceb];
        #pragma unroll
        for (int k = 0; k < 4; k++){
          f32x4 cv = *(const f32x4*)&ce_s[(16*k + li + dc)*60 + ceb];
          #pragma unroll
          for (int e = 0; e < 4; e++){
            acc[k][0] += cv[e]*w0[e];
            acc[k][1] += cv[e]*w1[e];
            acc[k][2] += cv[e]*w2[e];
          }
        }
      }
      float w0a = w_s[((3*jg+0)*3+dc)*52 + 48], w0b = w_s[((3*jg+0)*3+dc)*52 + 49];
      float w1a = w_s[((3*jg+1)*3+dc)*52 + 48], w1b = w_s[((3*jg+1)*3+dc)*52 + 49];
      float w2a = w_s[((3*jg+2)*3+dc)*52 + 48], w2b = w_s[((3*jg+2)*3+dc)*52 + 49];
      #pragma unroll
      for (int k = 0; k < 4; k++){
        float ca = ce_s[(16*k + li + dc)*60 + 48];
        float cb2 = ce_s[(16*k + li + dc)*60 + 49];
        acc[k][0] += ca*w0a + cb2*w0b;
        acc[k][1] += ca*w1a + cb2*w1b;
        acc[k][2] += ca*w2a + cb2*w2b;
      }
    }
    #pragma unroll
    for (int m = 1; m < 16; m <<= 1)
      #pragma unroll
      for (int k=0;k<4;k++)
        #pragma unroll
        for (int c=0;c<3;c++)
          acc[k][c] = fmaxf(acc[k][c], __shfl_xor(acc[k][c], m, 64));
    if (li == 0){
      #pragma unroll
      for (int k=0;k<4;k++)
        #pragma unroll
        for (int c=0;c<3;c++){
          int cc = 3*jg + c;
          int s = sb*4 + k;
          feat[(size_t)(s*64 + b)*416 + 350 + cc] = f2bf(acc[k][c] + cb[cc]);
        }
    }
    if (tid < 128){
      int pl = tid & 63, cc = 48 + (tid >> 6);
      float a2 = 0.f;
      #pragma unroll
      for (int dc = 0; dc < 3; dc++){
        for (int ceb = 0; ceb < 48; ceb += 4){
          f32x4 wv = *(const f32x4*)&w_s[(cc*3 + dc)*52 + ceb];
          f32x4 cv = *(const f32x4*)&ce_s[(pl + dc)*60 + ceb];
          a2 += cv[0]*wv[0] + cv[1]*wv[1] + cv[2]*wv[2] + cv[3]*wv[3];
        }
        a2 += ce_s[(pl+dc)*60 + 48]*w_s[(cc*3+dc)*52 + 48]
            + ce_s[(pl+dc)*60 + 49]*w_s[(cc*3+dc)*52 + 49];
      }
      #pragma unroll
      for (int m = 1; m < 16; m <<= 1) a2 = fmaxf(a2, __shfl_xor(a2, m, 64));
      if ((tid & 15) == 0){
        int s = sb*4 + ((tid & 63) >> 4);
        feat[(size_t)(s*64 + b)*416 + 350 + cc] = f2bf(a2 + cb[cc]);
      }
    }
  }
}

// ---------------- K2: gi = bf16(feat @ wih^T + bias), double-buffered LDS ----------------
// 2-phase pipeline: stage(k+1) issued BEFORE compute(k); ONE barrier per K-iter.
__global__ __launch_bounds__(256) void k2_gemm(
    const u16* __restrict__ featp, const u16* __restrict__ wihp,
    const float* __restrict__ bias, u16* __restrict__ gi)
{
  const int m0 = blockIdx.y*128, n0 = blockIdx.x*128;
  const int tid = threadIdx.x, wv = tid>>6, lane = tid&63;
  const int lr = lane & 15, lq = lane >> 4;
  const int wm = (wv>>1)*64, wn = (wv&1)*64;
  __shared__ u16 As[2][4096], Bs[2][4096];
  f32x4 acc[4][4];
  #pragma unroll
  for (int a=0;a<4;a++)
    #pragma unroll
    for (int c=0;c<4;c++) acc[a][c] = (f32x4){0.f,0.f,0.f,0.f};

  const size_t arow = (size_t)(m0 + ((wv)*16) + (lane>>2))*416 + (lane&3)*8;
  const size_t brow = (size_t)(n0 + ((wv)*16) + (lane>>2))*416 + (lane&3)*8;
  // stage(buf, k0): 2 chunks of 4 rows-groups per wave for A and B
  #define K2_STAGE(BUF, K0) { \
    _Pragma("unroll") \
    for (int i = 0; i < 2; i++){ \
      int c = i*4 + wv; \
      gld_lds16(featp + (size_t)(m0 + c*16 + (lane>>2))*416 + (K0) + (lane&3)*8, &As[BUF][c*512]); \
      gld_lds16(wihp  + (size_t)(n0 + c*16 + (lane>>2))*416 + (K0) + (lane&3)*8, &Bs[BUF][c*512]); \
    } }

  K2_STAGE(0, 0);
  __syncthreads();
  int buf = 0;
  for (int ki = 0; ki < 13; ki++){
    if (ki < 12) K2_STAGE(buf^1, (ki+1)*32);
    short8 af[4], bfr[4];
    #pragma unroll
    for (int mt=0; mt<4; mt++) af[mt]  = *(const short8*)(&As[buf][0] + (wm + mt*16 + lr)*32 + lq*8);
    #pragma unroll
    for (int nt=0; nt<4; nt++) bfr[nt] = *(const short8*)(&Bs[buf][0] + (wn + nt*16 + lr)*32 + lq*8);
    #pragma unroll
    for (int mt=0; mt<4; mt++)
      #pragma unroll
      for (int nt=0; nt<4; nt++)
        acc[mt][nt] = __builtin_amdgcn_mfma_f32_16x16x32_bf16(af[mt], bfr[nt], acc[mt][nt], 0,0,0);
    __syncthreads();   // drains vmcnt (stage buf^1 complete) + lgkm
    buf ^= 1;
  }
  #undef K2_STAGE
  (void)arow; (void)brow;
  #pragma unroll
  for (int nt=0; nt<4; nt++){
    float bv = bias[n0 + wn + nt*16 + lr];
    #pragma unroll
    for (int mt=0; mt<4; mt++)
      #pragma unroll
      for (int r=0; r<4; r++)
        gi[(size_t)(m0 + wm + mt*16 + lq*4 + r)*2048 + n0 + wn + nt*16 + lr]
            = f2bf(acc[mt][nt][r] + bv);
  }
}

// ---------------- K3: recurrent BiLSTM, 64 blocks x 512 thr, all-VGPR weights ----------------
__global__ __launch_bounds__(512, 2) void k3_lstm(
    const s8* __restrict__ wq, const float* __restrict__ sc2,
    const u16* __restrict__ gi, u16* __restrict__ hcat)
{
  const int dir = blockIdx.x >> 5;
  const int bb  = (blockIdx.x & 31) * 2;
  const int tid = threadIdx.x;
  const int w = tid >> 6, lane = tid & 63;
  const int lr = lane & 15, lq = lane >> 4;
  const int cb = tid >> 8, cj = tid & 255;

  __shared__ s8 Hs[2][4096];
  __shared__ float xbuf[2048];

  const s8* wqd = wq + dir*262144;
  int4v bq[2][4][4];
  #pragma unroll
  for (int sl = 0; sl < 2; sl++)
    #pragma unroll
    for (int g = 0; g < 4; g++)
      #pragma unroll
      for (int kk = 0; kk < 4; kk++)
        bq[sl][g][kk] = *(const int4v*)(wqd + (((((g*16 + 2*w + sl)*4 + kk)*64) + lane) << 4));

  float scl[4];
  #pragma unroll
  for (int g = 0; g < 4; g++) scl[g] = sc2[dir*1024 + g*256 + cj];

  *(uint2*)&Hs[0][tid*8] = (uint2){0u,0u};
  *(uint2*)&Hs[1][tid*8] = (uint2){0u,0u};

  float cst = 0.f;
  const ptrdiff_t dstep = dir ? -(ptrdiff_t)131072 : (ptrdiff_t)131072;
  const u16* g0 = gi + (size_t)((dir ? 511 : 0)*64 + bb + cb)*2048 + dir*1024 + cj;
  u32 gcur[4], gn1[4], gn2[4];
  #pragma unroll
  for (int g = 0; g < 4; g++) gcur[g] = g0[g*256];
  const u16* g1 = g0 + dstep;
  #pragma unroll
  for (int g = 0; g < 4; g++) gn1[g] = g1[g*256];
  const u16* gpref = g1;
  __syncthreads();

  #pragma unroll 1
  for (int t = 0; t < 512; t++){
    const int s = dir ? (511 - t) : t;
    if (t + 2 < 512) gpref += dstep;
    #pragma unroll
    for (int g = 0; g < 4; g++) gn2[g] = gpref[g*256];
    const s8* hb = Hs[t & 1];
    int4v aq[4];
    #pragma unroll
    for (int kk = 0; kk < 4; kk++)
      aq[kk] = *(const int4v*)(hb + lr*256 + ((kk*64 + lq*16) ^ (lr << 4)));
    int4v acc[2][4];
    #pragma unroll
    for (int sl = 0; sl < 2; sl++)
      #pragma unroll
      for (int g = 0; g < 4; g++) acc[sl][g] = (int4v){0,0,0,0};
    __builtin_amdgcn_s_setprio(1);
    #pragma unroll
    for (int kk = 0; kk < 4; kk++)
      #pragma unroll
      for (int sl = 0; sl < 2; sl++)
        #pragma unroll
        for (int g = 0; g < 4; g++)
          acc[sl][g] = __builtin_amdgcn_mfma_i32_16x16x64_i8(aq[kk], bq[sl][g][kk], acc[sl][g], 0,0,0);
    __builtin_amdgcn_s_setprio(0);
    if (lq == 0){
      #pragma unroll
      for (int sl = 0; sl < 2; sl++){
        const int j = (2*w + sl)*16 + lr;
        #pragma unroll
        for (int r = 0; r < 2; r++){
          f32x4 v = (f32x4){(float)acc[sl][0][r], (float)acc[sl][1][r],
                            (float)acc[sl][2][r], (float)acc[sl][3][r]};
          *(f32x4*)&xbuf[(r*256 + j)*4] = v;
        }
      }
    }
    bar_l();
    f32x4 p = *(const f32x4*)&xbuf[tid*4];
    float g4[4];
    #pragma unroll
    for (int g = 0; g < 4; g++) g4[g] = bf2f((u16)gcur[g]) + p[g]*scl[g];
    float iv = sigf(g4[0]), fv = sigf(g4[1]);
    float gg = tanh_f(g4[2]), ov = sigf(g4[3]);
    float c = fv*cst + iv*gg;
    cst = c;
    float h = ov * tanh_f(c);
    hcat[(size_t)(s*64 + bb + cb)*512 + dir*256 + cj] = f2bf(h);
    Hs[(t + 1) & 1][cb*256 + (cj ^ (cb << 4))] = (s8)(int)rintf(h * 127.f);
    #pragma unroll
    for (int g = 0; g < 4; g++){ gcur[g] = gn1[g]; gn1[g] = gn2[g]; }
    bar_l();
  }
}

// ---------------- K4: P = Hcat @ fc_w^T + fc_b + lm*wfc  [32768 x 16] fp32 ----------------
__global__ __launch_bounds__(256) void k4_fc(
    const u16* __restrict__ hcat, const float* __restrict__ fcw, const float* __restrict__ fcb,
    const float* __restrict__ lmp, const float* __restrict__ wfc, float* __restrict__ Pout)
{
  const int wv = threadIdx.x >> 6, lane = threadIdx.x & 63;
  const int lr = lane & 15, lq = lane >> 4;
  const int mt = blockIdx.x*4 + wv;
  short8 bfr[16];
  #pragma unroll
  for (int kk = 0; kk < 16; kk++){
    const float* wr = fcw + (size_t)lr*512 + kk*32 + lq*8;
    f32x4 w0 = *(const f32x4*)wr;
    f32x4 w1 = *(const f32x4*)(wr + 4);
    short8 sv;
    #pragma unroll
    for (int e = 0; e < 4; e++){ sv[e] = (short)f2bf(w0[e]); sv[4+e] = (short)f2bf(w1[e]); }
    bfr[kk] = sv;
  }
  f32x4 acc = (f32x4){0.f,0.f,0.f,0.f};
  #pragma unroll
  for (int kk = 0; kk < 16; kk++){
    short8 af = *(const short8*)(hcat + (size_t)(mt*16 + lr)*512 + kk*32 + lq*8);
    acc = __builtin_amdgcn_mfma_f32_16x16x32_bf16(af, bfr[kk], acc, 0,0,0);
  }
  const int cur = lr;
  float fb = fcb[cur];
  float wf = wfc[cur];
  #pragma unroll
  for (int r = 0; r < 4; r++){
    int m = mt*16 + lq*4 + r;
    int b = m & 63, s = m >> 6;
    float lmv = lmp[b*512 + s];
    Pout[(size_t)m*16 + cur] = acc[r] + fb + lmv*wf;
  }
}

// ---------------- K5: Viterbi — shuffle-free (replicated delta + readlane) ----------------
__global__ __launch_bounds__(64) void k5_vit(
    const float* __restrict__ Pg, const float* __restrict__ Am,
    float* __restrict__ dout, float* __restrict__ dl, u8* __restrict__ psi)
{
  const int b = blockIdx.x, lane = threadIdx.x;
  const int cur = lane & 15;
  float Ar[16];
  #pragma unroll
  for (int p = 0; p < 16; p++) Ar[p] = Am[p*16 + cur];
  float dreg[16];
  {
    float v0 = Pg[(size_t)b*16 + cur];
    if (lane < 16) dl[(size_t)b*16 + cur] = v0;
    #pragma unroll
    for (int c = 0; c < 16; c++) dreg[c] = rdlane_f(v0, c);
  }

#define FSTEP(X, S) { \
    float v_[16]; \
    _Pragma("unroll") \
    for (int p = 0; p < 16; p++) v_[p] = dreg[p] + Ar[p]; \
    float m1[8]; int i1[8]; \
    _Pragma("unroll") \
    for (int k = 0; k < 8; k++){ bool c_ = v_[2*k] >= v_[2*k+1]; \
      m1[k] = c_ ? v_[2*k] : v_[2*k+1]; i1[k] = c_ ? 2*k : 2*k+1; } \
    float m2[4]; int i2[4]; \
    _Pragma("unroll") \
    for (int k = 0; k < 4; k++){ bool c_ = m1[2*k] >= m1[2*k+1]; \
      m2[k] = c_ ? m1[2*k] : m1[2*k+1]; i2[k] = c_ ? i1[2*k] : i1[2*k+1]; } \
    float m3[2]; int i3[2]; \
    _Pragma("unroll") \
    for (int k = 0; k < 2; k++){ bool c_ = m2[2*k] >= m2[2*k+1]; \
      m3[k] = c_ ? m2[2*k] : m2[2*k+1]; i3[k] = c_ ? i2[2*k] : i2[2*k+1]; } \
    bool cf_ = m3[0] >= m3[1]; \
    float best = (cf_ ? m3[0] : m3[1]) + (X); \
    int bi = cf_ ? i3[0] : i3[1]; \
    if (lane < 16){ \
      dl[(size_t)((S)*64 + b)*16 + cur] = best; \
      psi[(size_t)((S)*64 + b)*16 + cur] = (u8)bi; \
    } \
    _Pragma("unroll") \
    for (int c = 0; c < 16; c++) dreg[c] = rdlane_f(best, c); \
  }

  float x0 = Pg[(size_t)(1*64 + b)*16 + cur];
  float x1 = Pg[(size_t)(2*64 + b)*16 + cur];
  float x2 = Pg[(size_t)(3*64 + b)*16 + cur];
  float x3 = Pg[(size_t)(4*64 + b)*16 + cur];
  for (int s = 1; s < 512; s += 4){
    FSTEP(x0, s);
    if (s + 4 < 512) x0 = Pg[(size_t)((s+4)*64 + b)*16 + cur];
    if (s + 1 < 512) FSTEP(x1, s+1);
    if (s + 5 < 512) x1 = Pg[(size_t)((s+5)*64 + b)*16 + cur];
    if (s + 2 < 512) FSTEP(x2, s+2);
    if (s + 6 < 512) x2 = Pg[(size_t)((s+6)*64 + b)*16 + cur];
    if (s + 3 < 512) FSTEP(x3, s+3);
    if (s + 7 < 512) x3 = Pg[(size_t)((s+7)*64 + b)*16 + cur];
  }
#undef FSTEP

  float bv = dreg[0]; int bix = 0;
  #pragma unroll
  for (int c = 1; c < 16; c++){ if (dreg[c] > bv){ bv = dreg[c]; bix = c; } }
  int tag = bix;
  float score = bv;
  if (lane == 0) dout[b*512 + 511] = (float)tag;

#define BSTEP(PV, DV, T) { \
    int prev = __builtin_amdgcn_readlane((PV), tag); \
    score += rdlane_f((DV), prev); \
    if (lane == 0) dout[b*512 + (T)] = (float)prev; \
    tag = prev; }

  int   p0 = 0, p1 = 0, p2 = 0, p3 = 0;
  float d0 = 0.f, d1 = 0.f, d2 = 0.f, d3 = 0.f;
  if (lane < 16){
    p0 = psi[(size_t)(511*64 + b)*16 + lane]; d0 = dl[(size_t)(510*64 + b)*16 + lane];
    p1 = psi[(size_t)(510*64 + b)*16 + lane]; d1 = dl[(size_t)(509*64 + b)*16 + lane];
    p2 = psi[(size_t)(509*64 + b)*16 + lane]; d2 = dl[(size_t)(508*64 + b)*16 + lane];
    p3 = psi[(size_t)(508*64 + b)*16 + lane]; d3 = dl[(size_t)(507*64 + b)*16 + lane];
  }
  for (int t = 510; t >= 0; t -= 4){
    BSTEP(p0, d0, t);
    if (t - 4 >= 0 && lane < 16){
      p0 = psi[(size_t)((t-3)*64 + b)*16 + lane]; d0 = dl[(size_t)((t-4)*64 + b)*16 + lane];
    }
    if (t - 1 >= 0) BSTEP(p1, d1, t-1);
    if (t - 5 >= 0 && lane < 16){
      p1 = psi[(size_t)((t-4)*64 + b)*16 + lane]; d1 = dl[(size_t)((t-5)*64 + b)*16 + lane];
    }
    if (t - 2 >= 0) BSTEP(p2, d2, t-2);
    if (t - 6 >= 0 && lane < 16){
      p2 = psi[(size_t)((t-5)*64 + b)*16 + lane]; d2 = dl[(size_t)((t-6)*64 + b)*16 + lane];
    }
    if (t - 3 >= 0) BSTEP(p3, d3, t-3);
    if (t - 7 >= 0 && lane < 16){
      p3 = psi[(size_t)((t-6)*64 + b)*16 + lane]; d3 = dl[(size_t)((t-7)*64 + b)*16 + lane];
    }
  }
#undef BSTEP
  if (lane == 0) dout[32768 + b] = score;
}

// ---------------- launcher ----------------
extern "C" void kernel_launch(void* const* d_in, const int* in_sizes, int n_in,
                              void* d_out, int out_size, void* d_ws, size_t ws_size,
                              hipStream_t stream)
{
  (void)in_sizes; (void)n_in; (void)out_size;
  if (ws_size < REQUIRED) return;

  const int*   X    = (const int*)d_in[0];
  const float* lm   = (const float*)d_in[1];
  const int*   tg   = (const int*)d_in[2];
  const int*   ch   = (const int*)d_in[3];
  const float* etab = (const float*)d_in[4];
  const float* ttab = (const float*)d_in[5];
  const float* ctab = (const float*)d_in[6];
  const float* cw   = (const float*)d_in[7];
  const float* cb   = (const float*)d_in[8];
  const float* wihf = (const float*)d_in[9];
  const float* whhf = (const float*)d_in[10];
  const float* bihf = (const float*)d_in[11];
  const float* bhhf = (const float*)d_in[12];
  const float* wihb = (const float*)d_in[13];
  const float* whhb = (const float*)d_in[14];
  const float* bihb = (const float*)d_in[15];
  const float* bhhb = (const float*)d_in[16];
  const float* fcw  = (const float*)d_in[17];
  const float* fcb  = (const float*)d_in[18];
  const float* Am   = (const float*)d_in[19];
  const float* wdp  = (const float*)d_in[20];

  char* ws = (char*)d_ws;
  u16*   gi   = (u16*)(ws + OFF_GI);
  u16*   feat = (u16*)(ws + OFF_B);
  u16*   hcat = (u16*)(ws + OFF_B);
  u16*   wih  = (u16*)(ws + OFF_WIH);
  s8*    wq   = (s8*)(ws + OFF_WQ);
  float* sc2  = (float*)(ws + OFF_SC);
  float* Pg   = (float*)(ws + OFF_P);
  float* dlt  = (float*)(ws + OFF_DL);
  u8*    psi  = (u8*)(ws + OFF_PSI);
  float* bias = (float*)(ws + OFF_BIAS);
  float* wfc  = (float*)(ws + OFF_WFC);
  float* dout = (float*)d_out;

  k0_all<<<2561, 256, 0, stream>>>(whhf, whhb, wq, sc2,
                                   bihf, bhhf, bihb, bhhb, fcw, wdp, bias, wfc,
                                   wihf, wihb, wih);
  k1_feat<<<dim3(16, 64), 256, 0, stream>>>(X, tg, ch, etab, ttab, ctab, cw, cb, feat);
  k2_gemm<<<dim3(16, 256), 256, 0, stream>>>(feat, wih, bias, gi);
  k3_lstm<<<64, 512, 0, stream>>>(wq, sc2, gi, hcat);
  k4_fc<<<512, 256, 0, stream>>>(hcat, fcw, fcb, lm, wfc, Pg);
  k5_vit<<<64, 64, 0, stream>>>(Pg, Am, dout, dlt, psi);
}